// Round 1
// baseline (2395.776 us; speedup 1.0000x reference)
//
#include <hip/hip_runtime.h>

#define H_ 8
#define B_ 32
#define L_ 1024
#define D_ 64
#define M_ 512
#define NR_ 32768  // B_*L_

// ---------------------------------------------------------------------------
// Kernel A: fused QKV projection.
// C[g][n][d] = sum_m A[n][m] * W[g][m][d] + bias[g*64+d],  g = t*H+h in 0..23
// Viewed as one GEMM (32768 x 512) x (512 x 1536). 128x128 tile, 8x8/thread.
// ---------------------------------------------------------------------------
__global__ __launch_bounds__(256) void qkv_gemm(
    const float* __restrict__ A,      // (32768, 512)
    const float* __restrict__ W,      // (24, 512, 64)
    const float* __restrict__ bias,   // (1536)
    float* __restrict__ C)            // (24, 32768, 64)
{
  __shared__ float As[16][132];   // [k][row]  (transposed A tile), stride 132: 2-way max
  __shared__ float Bs[16][132];   // [k][col]
  const int t  = threadIdx.x;
  const int tx = t & 15, ty = t >> 4;
  const int col0 = blockIdx.x * 128;
  const int row0 = blockIdx.y * 128;

  const int a_row = t >> 2;          // 0..63 (and +64)
  const int a_k4  = (t & 3) << 2;    // 0,4,8,12
  const int b_k   = t >> 5;          // 0..7 (and +8)
  const int b_c   = (t & 31) << 2;   // 0..124

  const int cc0 = col0 + b_c;
  const float* wp = &W[(size_t)(cc0 >> 6) * (M_ * D_) + (cc0 & 63)];

  float acc[8][8] = {{0.f}};

  // prefetch k0 = 0
  float4 av0 = *(const float4*)&A[(size_t)(row0 + a_row) * M_ + a_k4];
  float4 av1 = *(const float4*)&A[(size_t)(row0 + a_row + 64) * M_ + a_k4];
  float4 bv0 = *(const float4*)&wp[(size_t)b_k * D_];
  float4 bv1 = *(const float4*)&wp[(size_t)(b_k + 8) * D_];

  for (int k0 = 0; k0 < M_; k0 += 16) {
    As[a_k4 + 0][a_row]      = av0.x;
    As[a_k4 + 1][a_row]      = av0.y;
    As[a_k4 + 2][a_row]      = av0.z;
    As[a_k4 + 3][a_row]      = av0.w;
    As[a_k4 + 0][a_row + 64] = av1.x;
    As[a_k4 + 1][a_row + 64] = av1.y;
    As[a_k4 + 2][a_row + 64] = av1.z;
    As[a_k4 + 3][a_row + 64] = av1.w;
    *(float4*)&Bs[b_k][b_c]     = bv0;
    *(float4*)&Bs[b_k + 8][b_c] = bv1;
    __syncthreads();
    if (k0 + 16 < M_) {  // prefetch next K-slab while computing this one
      av0 = *(const float4*)&A[(size_t)(row0 + a_row) * M_ + k0 + 16 + a_k4];
      av1 = *(const float4*)&A[(size_t)(row0 + a_row + 64) * M_ + k0 + 16 + a_k4];
      bv0 = *(const float4*)&wp[(size_t)(k0 + 16 + b_k) * D_];
      bv1 = *(const float4*)&wp[(size_t)(k0 + 16 + b_k + 8) * D_];
    }
    #pragma unroll
    for (int kk = 0; kk < 16; ++kk) {
      float4 x0 = *(const float4*)&As[kk][ty << 2];
      float4 x1 = *(const float4*)&As[kk][64 + (ty << 2)];
      float4 y0 = *(const float4*)&Bs[kk][tx << 2];
      float4 y1 = *(const float4*)&Bs[kk][64 + (tx << 2)];
      float a[8] = {x0.x, x0.y, x0.z, x0.w, x1.x, x1.y, x1.z, x1.w};
      float b[8] = {y0.x, y0.y, y0.z, y0.w, y1.x, y1.y, y1.z, y1.w};
      #pragma unroll
      for (int i = 0; i < 8; ++i)
        #pragma unroll
        for (int j = 0; j < 8; ++j)
          acc[i][j] = fmaf(a[i], b[j], acc[i][j]);
    }
    __syncthreads();
  }

  #pragma unroll
  for (int i = 0; i < 8; ++i) {
    int r = row0 + ((i & 4) << 4) + (ty << 2) + (i & 3);
    #pragma unroll
    for (int jg = 0; jg < 2; ++jg) {
      int cc = col0 + (jg << 6) + (tx << 2);
      float4 v;
      v.x = acc[i][jg * 4 + 0] + bias[cc + 0];
      v.y = acc[i][jg * 4 + 1] + bias[cc + 1];
      v.z = acc[i][jg * 4 + 2] + bias[cc + 2];
      v.w = acc[i][jg * 4 + 3] + bias[cc + 3];
      *(float4*)&C[(size_t)(cc >> 6) * ((size_t)NR_ * D_) + (size_t)r * D_ + (cc & 63)] = v;
    }
  }
}

// ---------------------------------------------------------------------------
// Kernel B: flash attention (fp32). One block = one (h,b) x 64 query rows.
// Online softmax in registers (16-lane shuffle reductions). Scores include
// additive mask (broadcast over h,b). Output written as (B*L, H*D).
// ---------------------------------------------------------------------------
__global__ __launch_bounds__(256) void attn_fwd(
    const float* __restrict__ qkv,    // (24, 32768, 64): q=g<8, k=8+h, v=16+h
    const float* __restrict__ mask,   // (1024, 1024)
    float* __restrict__ outa)         // (32768, 512)
{
  __shared__ float Qt[64][68];   // [d][r]
  __shared__ float Kt[64][68];   // [d][c]
  __shared__ float Vs[64][68];   // [kk][d]
  __shared__ float Ps[64][68];   // [r][kk]

  const int t  = threadIdx.x;
  const int tx = t & 15, ty = t >> 4;
  const int qt = blockIdx.x;   // 0..15
  const int b  = blockIdx.y;   // 0..31
  const int h  = blockIdx.z;   // 0..7

  const float* Qp = qkv + ((size_t)h * NR_ + (size_t)b * L_ + qt * 64) * D_;
  const float* Kp = qkv + ((size_t)(8 + h) * NR_ + (size_t)b * L_) * D_;
  const float* Vp = qkv + ((size_t)(16 + h) * NR_ + (size_t)b * L_) * D_;

  // load + transpose Q tile (64x64)
  #pragma unroll
  for (int w = 0; w < 4; ++w) {
    int idx = t + 256 * w;
    int r = idx >> 4;
    int c4 = (idx & 15) << 2;
    float4 v = *(const float4*)(Qp + (size_t)r * D_ + c4);
    Qt[c4 + 0][r] = v.x; Qt[c4 + 1][r] = v.y;
    Qt[c4 + 2][r] = v.z; Qt[c4 + 3][r] = v.w;
  }

  float m_i[4], l_i[4];
  float O[4][4] = {{0.f}};
  #pragma unroll
  for (int i = 0; i < 4; ++i) { m_i[i] = -1e30f; l_i[i] = 0.f; }

  for (int kt = 0; kt < 16; ++kt) {
    __syncthreads();   // prev PV done; Kt/Vs/Ps free (also covers initial Q write)
    #pragma unroll
    for (int w = 0; w < 4; ++w) {
      int idx = t + 256 * w;
      int r = idx >> 4;
      int c4 = (idx & 15) << 2;
      float4 kv = *(const float4*)(Kp + (size_t)(kt * 64 + r) * D_ + c4);
      Kt[c4 + 0][r] = kv.x; Kt[c4 + 1][r] = kv.y;
      Kt[c4 + 2][r] = kv.z; Kt[c4 + 3][r] = kv.w;
      float4 vv = *(const float4*)(Vp + (size_t)(kt * 64 + r) * D_ + c4);
      *(float4*)&Vs[r][c4] = vv;
    }
    __syncthreads();

    // S = Q K^T (4x4 per thread)
    float S[4][4] = {{0.f}};
    #pragma unroll
    for (int d0 = 0; d0 < 64; ++d0) {
      float4 qv = *(const float4*)&Qt[d0][ty << 2];
      float4 kv = *(const float4*)&Kt[d0][tx << 2];
      float qa[4] = {qv.x, qv.y, qv.z, qv.w};
      float ka[4] = {kv.x, kv.y, kv.z, kv.w};
      #pragma unroll
      for (int i = 0; i < 4; ++i)
        #pragma unroll
        for (int j = 0; j < 4; ++j)
          S[i][j] = fmaf(qa[i], ka[j], S[i][j]);
    }

    // + mask, online softmax
    #pragma unroll
    for (int i = 0; i < 4; ++i) {
      const float* mrow = mask + (size_t)(qt * 64 + (ty << 2) + i) * L_ + kt * 64 + (tx << 2);
      float4 mv = *(const float4*)mrow;
      S[i][0] += mv.x; S[i][1] += mv.y; S[i][2] += mv.z; S[i][3] += mv.w;

      float tm = fmaxf(fmaxf(S[i][0], S[i][1]), fmaxf(S[i][2], S[i][3]));
      #pragma unroll
      for (int off = 8; off; off >>= 1) tm = fmaxf(tm, __shfl_xor(tm, off, 64));
      float mn = fmaxf(m_i[i], tm);
      float sc = __expf(m_i[i] - mn);
      float rs = 0.f;
      #pragma unroll
      for (int j = 0; j < 4; ++j) { S[i][j] = __expf(S[i][j] - mn); rs += S[i][j]; }
      #pragma unroll
      for (int off = 8; off; off >>= 1) rs += __shfl_xor(rs, off, 64);
      l_i[i] = l_i[i] * sc + rs;
      m_i[i] = mn;
      #pragma unroll
      for (int j = 0; j < 4; ++j) O[i][j] *= sc;
      float4 pv = {S[i][0], S[i][1], S[i][2], S[i][3]};
      *(float4*)&Ps[(ty << 2) + i][tx << 2] = pv;
    }
    __syncthreads();

    // O += P V
    #pragma unroll
    for (int k4 = 0; k4 < 64; k4 += 4) {
      float4 vr[4];
      #pragma unroll
      for (int u = 0; u < 4; ++u) vr[u] = *(const float4*)&Vs[k4 + u][tx << 2];
      #pragma unroll
      for (int i = 0; i < 4; ++i) {
        float4 p = *(const float4*)&Ps[(ty << 2) + i][k4];
        float pa[4] = {p.x, p.y, p.z, p.w};
        #pragma unroll
        for (int u = 0; u < 4; ++u) {
          O[i][0] = fmaf(pa[u], vr[u].x, O[i][0]);
          O[i][1] = fmaf(pa[u], vr[u].y, O[i][1]);
          O[i][2] = fmaf(pa[u], vr[u].z, O[i][2]);
          O[i][3] = fmaf(pa[u], vr[u].w, O[i][3]);
        }
      }
    }
  }

  #pragma unroll
  for (int i = 0; i < 4; ++i) {
    float inv = 1.0f / l_i[i];
    float4 v = {O[i][0] * inv, O[i][1] * inv, O[i][2] * inv, O[i][3] * inv};
    size_t row = (size_t)b * L_ + qt * 64 + (ty << 2) + i;
    *(float4*)&outa[row * M_ + h * 64 + (tx << 2)] = v;
  }
}

// ---------------------------------------------------------------------------
// Kernel C: post projection. C = A (32768x512) x W (512x512) + bias.
// ---------------------------------------------------------------------------
__global__ __launch_bounds__(256) void post_gemm(
    const float* __restrict__ A,
    const float* __restrict__ W,
    const float* __restrict__ bias,
    float* __restrict__ C)
{
  __shared__ float As[16][132];
  __shared__ float Bs[16][132];
  const int t  = threadIdx.x;
  const int tx = t & 15, ty = t >> 4;
  const int col0 = blockIdx.x * 128;
  const int row0 = blockIdx.y * 128;

  const int a_row = t >> 2;
  const int a_k4  = (t & 3) << 2;
  const int b_k   = t >> 5;
  const int b_c   = (t & 31) << 2;

  const float* wp = &W[col0 + b_c];

  float acc[8][8] = {{0.f}};

  float4 av0 = *(const float4*)&A[(size_t)(row0 + a_row) * M_ + a_k4];
  float4 av1 = *(const float4*)&A[(size_t)(row0 + a_row + 64) * M_ + a_k4];
  float4 bv0 = *(const float4*)&wp[(size_t)b_k * M_];
  float4 bv1 = *(const float4*)&wp[(size_t)(b_k + 8) * M_];

  for (int k0 = 0; k0 < M_; k0 += 16) {
    As[a_k4 + 0][a_row]      = av0.x;
    As[a_k4 + 1][a_row]      = av0.y;
    As[a_k4 + 2][a_row]      = av0.z;
    As[a_k4 + 3][a_row]      = av0.w;
    As[a_k4 + 0][a_row + 64] = av1.x;
    As[a_k4 + 1][a_row + 64] = av1.y;
    As[a_k4 + 2][a_row + 64] = av1.z;
    As[a_k4 + 3][a_row + 64] = av1.w;
    *(float4*)&Bs[b_k][b_c]     = bv0;
    *(float4*)&Bs[b_k + 8][b_c] = bv1;
    __syncthreads();
    if (k0 + 16 < M_) {
      av0 = *(const float4*)&A[(size_t)(row0 + a_row) * M_ + k0 + 16 + a_k4];
      av1 = *(const float4*)&A[(size_t)(row0 + a_row + 64) * M_ + k0 + 16 + a_k4];
      bv0 = *(const float4*)&wp[(size_t)(k0 + 16 + b_k) * M_];
      bv1 = *(const float4*)&wp[(size_t)(k0 + 16 + b_k + 8) * M_];
    }
    #pragma unroll
    for (int kk = 0; kk < 16; ++kk) {
      float4 x0 = *(const float4*)&As[kk][ty << 2];
      float4 x1 = *(const float4*)&As[kk][64 + (ty << 2)];
      float4 y0 = *(const float4*)&Bs[kk][tx << 2];
      float4 y1 = *(const float4*)&Bs[kk][64 + (tx << 2)];
      float a[8] = {x0.x, x0.y, x0.z, x0.w, x1.x, x1.y, x1.z, x1.w};
      float b[8] = {y0.x, y0.y, y0.z, y0.w, y1.x, y1.y, y1.z, y1.w};
      #pragma unroll
      for (int i = 0; i < 8; ++i)
        #pragma unroll
        for (int j = 0; j < 8; ++j)
          acc[i][j] = fmaf(a[i], b[j], acc[i][j]);
    }
    __syncthreads();
  }

  #pragma unroll
  for (int i = 0; i < 8; ++i) {
    int r = row0 + ((i & 4) << 4) + (ty << 2) + (i & 3);
    #pragma unroll
    for (int jg = 0; jg < 2; ++jg) {
      int cc = col0 + (jg << 6) + (tx << 2);
      float4 v;
      v.x = acc[i][jg * 4 + 0] + bias[cc + 0];
      v.y = acc[i][jg * 4 + 1] + bias[cc + 1];
      v.z = acc[i][jg * 4 + 2] + bias[cc + 2];
      v.w = acc[i][jg * 4 + 3] + bias[cc + 3];
      *(float4*)&C[(size_t)r * M_ + cc] = v;
    }
  }
}

extern "C" void kernel_launch(void* const* d_in, const int* in_sizes, int n_in,
                              void* d_out, int out_size, void* d_ws, size_t ws_size,
                              hipStream_t stream) {
  const float* inp    = (const float*)d_in[0];
  const float* mask   = (const float*)d_in[1];
  const float* pre_w  = (const float*)d_in[2];
  const float* pre_b  = (const float*)d_in[3];
  const float* post_w = (const float*)d_in[4];
  const float* post_b = (const float*)d_in[5];
  float* out = (float*)d_out;

  // workspace: qkv (24,32768,64) fp32 = 201.3 MB, attn_out (32768,512) = 67.1 MB
  float* qkv      = (float*)d_ws;
  float* attn_out = qkv + (size_t)24 * NR_ * D_;

  qkv_gemm<<<dim3(12, 256), 256, 0, stream>>>(inp, pre_w, pre_b, qkv);
  attn_fwd<<<dim3(16, 32, 8), 256, 0, stream>>>(qkv, mask, attn_out);
  post_gemm<<<dim3(4, 256), 256, 0, stream>>>(attn_out, post_w, post_b, out);
}

// Round 2
// 1100.958 us; speedup vs baseline: 2.1761x; 2.1761x over previous
//
#include <hip/hip_runtime.h>

#define H_ 8
#define B_ 32
#define L_ 1024
#define D_ 64
#define M_ 512
#define NR_ 32768  // B_*L_

typedef _Float16 half8 __attribute__((ext_vector_type(8)));
typedef _Float16 half4 __attribute__((ext_vector_type(4)));
typedef float f32x16 __attribute__((ext_vector_type(16)));
typedef unsigned int uint2v __attribute__((ext_vector_type(2)));
typedef unsigned int uint4v __attribute__((ext_vector_type(4)));

#define MFMA32(A, B, C) __builtin_amdgcn_mfma_f32_32x32x16_f16(A, B, C, 0, 0, 0)

static __device__ __forceinline__ unsigned pkh(float a, float b) {
  return __builtin_bit_cast(unsigned, __builtin_amdgcn_cvt_pkrtz(a, b));
}

// ---------------------------------------------------------------------------
// Kernel A: fused QKV projection (fp32 vector GEMM, unchanged core).
// Epilogue: bias add in fp32, then split q,k into fp16 hi+lo; v as fp16.
// ---------------------------------------------------------------------------
__global__ __launch_bounds__(256) void qkv_gemm(
    const float* __restrict__ A,      // (32768, 512)
    const float* __restrict__ W,      // (24, 512, 64)
    const float* __restrict__ bias,   // (1536)
    _Float16* __restrict__ q_hi, _Float16* __restrict__ q_lo,
    _Float16* __restrict__ k_hi, _Float16* __restrict__ k_lo,
    _Float16* __restrict__ v_h)       // each (8, 32768, 64)
{
  __shared__ float As[16][132];
  __shared__ float Bs[16][132];
  const int t  = threadIdx.x;
  const int tx = t & 15, ty = t >> 4;
  const int col0 = blockIdx.x * 128;
  const int row0 = blockIdx.y * 128;

  const int a_row = t >> 2;
  const int a_k4  = (t & 3) << 2;
  const int b_k   = t >> 5;
  const int b_c   = (t & 31) << 2;

  const int cc0 = col0 + b_c;
  const float* wp = &W[(size_t)(cc0 >> 6) * (M_ * D_) + (cc0 & 63)];

  float acc[8][8] = {{0.f}};

  float4 av0 = *(const float4*)&A[(size_t)(row0 + a_row) * M_ + a_k4];
  float4 av1 = *(const float4*)&A[(size_t)(row0 + a_row + 64) * M_ + a_k4];
  float4 bv0 = *(const float4*)&wp[(size_t)b_k * D_];
  float4 bv1 = *(const float4*)&wp[(size_t)(b_k + 8) * D_];

  for (int k0 = 0; k0 < M_; k0 += 16) {
    As[a_k4 + 0][a_row]      = av0.x;
    As[a_k4 + 1][a_row]      = av0.y;
    As[a_k4 + 2][a_row]      = av0.z;
    As[a_k4 + 3][a_row]      = av0.w;
    As[a_k4 + 0][a_row + 64] = av1.x;
    As[a_k4 + 1][a_row + 64] = av1.y;
    As[a_k4 + 2][a_row + 64] = av1.z;
    As[a_k4 + 3][a_row + 64] = av1.w;
    *(float4*)&Bs[b_k][b_c]     = bv0;
    *(float4*)&Bs[b_k + 8][b_c] = bv1;
    __syncthreads();
    if (k0 + 16 < M_) {
      av0 = *(const float4*)&A[(size_t)(row0 + a_row) * M_ + k0 + 16 + a_k4];
      av1 = *(const float4*)&A[(size_t)(row0 + a_row + 64) * M_ + k0 + 16 + a_k4];
      bv0 = *(const float4*)&wp[(size_t)(k0 + 16 + b_k) * D_];
      bv1 = *(const float4*)&wp[(size_t)(k0 + 16 + b_k + 8) * D_];
    }
    #pragma unroll
    for (int kk = 0; kk < 16; ++kk) {
      float4 x0 = *(const float4*)&As[kk][ty << 2];
      float4 x1 = *(const float4*)&As[kk][64 + (ty << 2)];
      float4 y0 = *(const float4*)&Bs[kk][tx << 2];
      float4 y1 = *(const float4*)&Bs[kk][64 + (tx << 2)];
      float a[8] = {x0.x, x0.y, x0.z, x0.w, x1.x, x1.y, x1.z, x1.w};
      float b[8] = {y0.x, y0.y, y0.z, y0.w, y1.x, y1.y, y1.z, y1.w};
      #pragma unroll
      for (int i = 0; i < 8; ++i)
        #pragma unroll
        for (int j = 0; j < 8; ++j)
          acc[i][j] = fmaf(a[i], b[j], acc[i][j]);
    }
    __syncthreads();
  }

  #pragma unroll
  for (int i = 0; i < 8; ++i) {
    int r = row0 + ((i & 4) << 4) + (ty << 2) + (i & 3);
    #pragma unroll
    for (int jg = 0; jg < 2; ++jg) {
      int cc = col0 + (jg << 6) + (tx << 2);
      int g = cc >> 6, d = cc & 63;
      int t3 = g >> 3, hd = g & 7;     // t3: 0=q 1=k 2=v; wave-uniform branch
      size_t base = ((size_t)hd * NR_ + (size_t)r) * D_ + d;
      half4 hi, lo;
      #pragma unroll
      for (int u = 0; u < 4; ++u) {
        float x = acc[i][jg * 4 + u] + bias[cc + u];
        _Float16 hx = (_Float16)x;
        hi[u] = hx;
        lo[u] = (_Float16)(x - (float)hx);
      }
      if (t3 == 0)      { *(half4*)(q_hi + base) = hi; *(half4*)(q_lo + base) = lo; }
      else if (t3 == 1) { *(half4*)(k_hi + base) = hi; *(half4*)(k_lo + base) = lo; }
      else              { *(half4*)(v_h  + base) = hi; }
    }
  }
}

// ---------------------------------------------------------------------------
// Kernel B: MFMA flash attention. Block = (qt,b,h), 4 waves x 32 q = 128 q.
// S^T = mfma(K, Q) (32x32x16 f16, fp32 acc, hi/lo split x3).
// Softmax in-register (lane owns one q-column). P^T B-frags built via
// cvt_pkrtz + permlane32_swap (no LDS round-trip). O^T = mfma(V^T, P^T).
// ---------------------------------------------------------------------------
__global__ __launch_bounds__(256) void attn_mfma(
    const _Float16* __restrict__ qh, const _Float16* __restrict__ ql,
    const _Float16* __restrict__ kh, const _Float16* __restrict__ kl,
    const _Float16* __restrict__ vh,
    const float* __restrict__ mask,   // (1024, 1024)
    float* __restrict__ outa)         // (32768, 512)
{
  __shared__ _Float16 Khi[64 * 72];   // [k][d], 72-half rows: 16B-aligned
  __shared__ _Float16 Klo[64 * 72];
  __shared__ _Float16 Vt [64 * 72];   // [d][k]

  const int t    = threadIdx.x;
  const int lane = t & 63, w = t >> 6;          // 4 waves
  const int lq   = lane & 31, hh = lane >> 5;   // q col, k-half
  const int qt = blockIdx.x;                    // 0..7
  const int b  = blockIdx.y;                    // 0..31
  const int hd = blockIdx.z;                    // 0..7

  const int q_row = qt * 128 + w * 32 + lq;     // 0..1023 within batch b
  const size_t headoff = (size_t)hd * NR_ * D_ + (size_t)b * L_ * D_;

  // Q B-fragments in registers (hi & lo), 4 K-dim chunks of 16
  const size_t qbase = headoff + (size_t)q_row * D_;
  half8 Qhc[4], Qlc[4];
  #pragma unroll
  for (int c = 0; c < 4; ++c) {
    Qhc[c] = *(const half8*)(qh + qbase + c * 16 + hh * 8);
    Qlc[c] = *(const half8*)(ql + qbase + c * 16 + hh * 8);
  }

  const _Float16* Kph = kh + headoff;
  const _Float16* Kpl = kl + headoff;
  const _Float16* Vp  = vh + headoff;
  const float*   mrow = mask + (size_t)q_row * L_;

  // staging indices: thread -> (row 0..63, half-offset 0/16/32/48)
  const int srow = t >> 2;
  const int soff = (t & 3) * 16;

  float m_i = -3.0e38f, l_i = 0.f;
  f32x16 O0, O1;
  #pragma unroll
  for (int i = 0; i < 16; ++i) { O0[i] = 0.f; O1[i] = 0.f; }

  for (int kt = 0; kt < 16; ++kt) {
    __syncthreads();
    // ---- stage K_hi, K_lo, V^T (64 x 64 halves each) ----
    const size_t goff = (size_t)(kt * 64 + srow) * D_ + soff;
    *(half8*)&Khi[srow * 72 + soff]     = *(const half8*)(Kph + goff);
    *(half8*)&Khi[srow * 72 + soff + 8] = *(const half8*)(Kph + goff + 8);
    *(half8*)&Klo[srow * 72 + soff]     = *(const half8*)(Kpl + goff);
    *(half8*)&Klo[srow * 72 + soff + 8] = *(const half8*)(Kpl + goff + 8);
    half8 va = *(const half8*)(Vp + goff);
    half8 vb = *(const half8*)(Vp + goff + 8);
    #pragma unroll
    for (int j = 0; j < 8; ++j) {
      Vt[(soff + j) * 72 + srow]     = va[j];
      Vt[(soff + 8 + j) * 72 + srow] = vb[j];
    }
    __syncthreads();

    // ---- S^T (64 k x 32 q), two 32-row subtiles ----
    f32x16 S[2];
    #pragma unroll
    for (int s2 = 0; s2 < 2; ++s2) {
      f32x16 acc;
      #pragma unroll
      for (int i = 0; i < 16; ++i) acc[i] = 0.f;
      #pragma unroll
      for (int c = 0; c < 4; ++c) {
        half8 ah = *(const half8*)&Khi[(s2 * 32 + lq) * 72 + c * 16 + hh * 8];
        half8 al = *(const half8*)&Klo[(s2 * 32 + lq) * 72 + c * 16 + hh * 8];
        acc = MFMA32(ah, Qhc[c], acc);
        acc = MFMA32(ah, Qlc[c], acc);
        acc = MFMA32(al, Qhc[c], acc);
      }
      S[s2] = acc;
    }

    // ---- + mask; online softmax (lane owns q = lq; partner lane shares) ----
    // element (s2, r) is k = kt*64 + s2*32 + 8*(r>>2) + 4*hh + (r&3)
    #pragma unroll
    for (int s2 = 0; s2 < 2; ++s2)
      #pragma unroll
      for (int m = 0; m < 4; ++m) {
        float4 mv = *(const float4*)(mrow + kt * 64 + s2 * 32 + m * 8 + hh * 4);
        S[s2][4 * m + 0] += mv.x;
        S[s2][4 * m + 1] += mv.y;
        S[s2][4 * m + 2] += mv.z;
        S[s2][4 * m + 3] += mv.w;
      }

    float tmax = -3.0e38f;
    #pragma unroll
    for (int s2 = 0; s2 < 2; ++s2)
      #pragma unroll
      for (int r = 0; r < 16; ++r) tmax = fmaxf(tmax, S[s2][r]);
    tmax = fmaxf(tmax, __shfl_xor(tmax, 32, 64));

    float mn = fmaxf(m_i, tmax);
    float sc = __expf(m_i - mn);
    m_i = mn;
    float rs = 0.f;
    #pragma unroll
    for (int s2 = 0; s2 < 2; ++s2)
      #pragma unroll
      for (int r = 0; r < 16; ++r) {
        float e = __expf(S[s2][r] - mn);
        S[s2][r] = e;
        rs += e;
      }
    rs += __shfl_xor(rs, 32, 64);
    l_i = l_i * sc + rs;
    O0 = O0 * sc;
    O1 = O1 * sc;

    // ---- O^T += V^T . P^T ; P^T frag per K-chunk via permlane32_swap ----
    #pragma unroll
    for (int kc = 0; kc < 4; ++kc) {
      const int s2 = kc >> 1, a2 = kc & 1;
      unsigned x0 = pkh(S[s2][8 * a2 + 0], S[s2][8 * a2 + 1]);
      unsigned x1 = pkh(S[s2][8 * a2 + 2], S[s2][8 * a2 + 3]);
      unsigned y0 = pkh(S[s2][8 * a2 + 4], S[s2][8 * a2 + 5]);
      unsigned y1 = pkh(S[s2][8 * a2 + 6], S[s2][8 * a2 + 7]);
      uint2v r0 = __builtin_amdgcn_permlane32_swap(x0, y0, false, false);
      uint2v r1 = __builtin_amdgcn_permlane32_swap(x1, y1, false, false);
      uint4v wv;
      wv.x = r0.x; wv.y = r1.x; wv.z = r0.y; wv.w = r1.y;
      half8 pfrag = __builtin_bit_cast(half8, wv);
      O0 = MFMA32(*(const half8*)&Vt[lq * 72 + kc * 16 + hh * 8], pfrag, O0);
      O1 = MFMA32(*(const half8*)&Vt[(32 + lq) * 72 + kc * 16 + hh * 8], pfrag, O1);
    }
  }

  // ---- epilogue: O / l, write (B*L, 512); d = ds*32 + 8m + 4hh + r ----
  float inv = 1.0f / l_i;
  float* orow = outa + ((size_t)b * L_ + q_row) * M_ + hd * 64;
  #pragma unroll
  for (int m = 0; m < 4; ++m) {
    float4 v0 = {O0[4 * m + 0] * inv, O0[4 * m + 1] * inv,
                 O0[4 * m + 2] * inv, O0[4 * m + 3] * inv};
    *(float4*)(orow + m * 8 + hh * 4) = v0;
    float4 v1 = {O1[4 * m + 0] * inv, O1[4 * m + 1] * inv,
                 O1[4 * m + 2] * inv, O1[4 * m + 3] * inv};
    *(float4*)(orow + 32 + m * 8 + hh * 4) = v1;
  }
}

// ---------------------------------------------------------------------------
// Kernel C: post projection (fp32 vector GEMM, unchanged).
// ---------------------------------------------------------------------------
__global__ __launch_bounds__(256) void post_gemm(
    const float* __restrict__ A,
    const float* __restrict__ W,
    const float* __restrict__ bias,
    float* __restrict__ C)
{
  __shared__ float As[16][132];
  __shared__ float Bs[16][132];
  const int t  = threadIdx.x;
  const int tx = t & 15, ty = t >> 4;
  const int col0 = blockIdx.x * 128;
  const int row0 = blockIdx.y * 128;

  const int a_row = t >> 2;
  const int a_k4  = (t & 3) << 2;
  const int b_k   = t >> 5;
  const int b_c   = (t & 31) << 2;

  const float* wp = &W[col0 + b_c];

  float acc[8][8] = {{0.f}};

  float4 av0 = *(const float4*)&A[(size_t)(row0 + a_row) * M_ + a_k4];
  float4 av1 = *(const float4*)&A[(size_t)(row0 + a_row + 64) * M_ + a_k4];
  float4 bv0 = *(const float4*)&wp[(size_t)b_k * M_];
  float4 bv1 = *(const float4*)&wp[(size_t)(b_k + 8) * M_];

  for (int k0 = 0; k0 < M_; k0 += 16) {
    As[a_k4 + 0][a_row]      = av0.x;
    As[a_k4 + 1][a_row]      = av0.y;
    As[a_k4 + 2][a_row]      = av0.z;
    As[a_k4 + 3][a_row]      = av0.w;
    As[a_k4 + 0][a_row + 64] = av1.x;
    As[a_k4 + 1][a_row + 64] = av1.y;
    As[a_k4 + 2][a_row + 64] = av1.z;
    As[a_k4 + 3][a_row + 64] = av1.w;
    *(float4*)&Bs[b_k][b_c]     = bv0;
    *(float4*)&Bs[b_k + 8][b_c] = bv1;
    __syncthreads();
    if (k0 + 16 < M_) {
      av0 = *(const float4*)&A[(size_t)(row0 + a_row) * M_ + k0 + 16 + a_k4];
      av1 = *(const float4*)&A[(size_t)(row0 + a_row + 64) * M_ + k0 + 16 + a_k4];
      bv0 = *(const float4*)&wp[(size_t)(k0 + 16 + b_k) * M_];
      bv1 = *(const float4*)&wp[(size_t)(k0 + 16 + b_k + 8) * M_];
    }
    #pragma unroll
    for (int kk = 0; kk < 16; ++kk) {
      float4 x0 = *(const float4*)&As[kk][ty << 2];
      float4 x1 = *(const float4*)&As[kk][64 + (ty << 2)];
      float4 y0 = *(const float4*)&Bs[kk][tx << 2];
      float4 y1 = *(const float4*)&Bs[kk][64 + (tx << 2)];
      float a[8] = {x0.x, x0.y, x0.z, x0.w, x1.x, x1.y, x1.z, x1.w};
      float b[8] = {y0.x, y0.y, y0.z, y0.w, y1.x, y1.y, y1.z, y1.w};
      #pragma unroll
      for (int i = 0; i < 8; ++i)
        #pragma unroll
        for (int j = 0; j < 8; ++j)
          acc[i][j] = fmaf(a[i], b[j], acc[i][j]);
    }
    __syncthreads();
  }

  #pragma unroll
  for (int i = 0; i < 8; ++i) {
    int r = row0 + ((i & 4) << 4) + (ty << 2) + (i & 3);
    #pragma unroll
    for (int jg = 0; jg < 2; ++jg) {
      int cc = col0 + (jg << 6) + (tx << 2);
      float4 v;
      v.x = acc[i][jg * 4 + 0] + bias[cc + 0];
      v.y = acc[i][jg * 4 + 1] + bias[cc + 1];
      v.z = acc[i][jg * 4 + 2] + bias[cc + 2];
      v.w = acc[i][jg * 4 + 3] + bias[cc + 3];
      *(float4*)&C[(size_t)r * M_ + cc] = v;
    }
  }
}

extern "C" void kernel_launch(void* const* d_in, const int* in_sizes, int n_in,
                              void* d_out, int out_size, void* d_ws, size_t ws_size,
                              hipStream_t stream) {
  const float* inp    = (const float*)d_in[0];
  const float* mask   = (const float*)d_in[1];
  const float* pre_w  = (const float*)d_in[2];
  const float* pre_b  = (const float*)d_in[3];
  const float* post_w = (const float*)d_in[4];
  const float* post_b = (const float*)d_in[5];
  float* out = (float*)d_out;

  // ws: 5 half arrays (8,32768,64) = 167.8 MB + attn_out f32 67.1 MB
  const size_t HNE = (size_t)H_ * NR_ * D_;   // 16,777,216 halves
  _Float16* q_hi = (_Float16*)d_ws;
  _Float16* q_lo = q_hi + HNE;
  _Float16* k_hi = q_lo + HNE;
  _Float16* k_lo = k_hi + HNE;
  _Float16* v_h  = k_lo + HNE;
  float* attn_out = (float*)(v_h + HNE);

  qkv_gemm<<<dim3(12, 256), 256, 0, stream>>>(inp, pre_w, pre_b,
                                              q_hi, q_lo, k_hi, k_lo, v_h);
  attn_mfma<<<dim3(8, 32, 8), 256, 0, stream>>>(q_hi, q_lo, k_hi, k_lo, v_h,
                                                mask, attn_out);
  post_gemm<<<dim3(4, 256), 256, 0, stream>>>(attn_out, post_w, post_b, out);
}

// Round 4
// 526.111 us; speedup vs baseline: 4.5537x; 2.0926x over previous
//
#include <hip/hip_runtime.h>

#define H_ 8
#define B_ 32
#define L_ 1024
#define D_ 64
#define M_ 512
#define NR_ 32768  // B_*L_

typedef _Float16 half8 __attribute__((ext_vector_type(8)));
typedef _Float16 half4 __attribute__((ext_vector_type(4)));
typedef float f32x16 __attribute__((ext_vector_type(16)));
typedef unsigned int uint2v __attribute__((ext_vector_type(2)));
typedef unsigned int uint4v __attribute__((ext_vector_type(4)));

#define MFMA32(A, B, C) __builtin_amdgcn_mfma_f32_32x32x16_f16(A, B, C, 0, 0, 0)

static __device__ __forceinline__ unsigned pkh(float a, float b) {
  return __builtin_bit_cast(unsigned, __builtin_amdgcn_cvt_pkrtz(a, b));
}
// LDS rows are 36 halves (72 B): only 8B-aligned, so move half8 as two half4s.
static __device__ __forceinline__ half8 lds_ld8(const _Float16* p) {
  half4 a = *(const half4*)p;
  half4 b = *(const half4*)(p + 4);
  return __builtin_shufflevector(a, b, 0, 1, 2, 3, 4, 5, 6, 7);
}
static __device__ __forceinline__ void lds_st8(_Float16* p, half8 v) {
  *(half4*)p       = __builtin_shufflevector(v, v, 0, 1, 2, 3);
  *(half4*)(p + 4) = __builtin_shufflevector(v, v, 4, 5, 6, 7);
}
struct half2s { _Float16 h, l; };
static __device__ __forceinline__ half2s split1(float x) {
  half2s r;
  r.h = (_Float16)x;
  r.l = (_Float16)(x - (float)r.h);
  return r;
}

// ---------------------------------------------------------------------------
// split_a: inp (32768x512 f32) -> a_hi, a_lo fp16 (same layout)
// ---------------------------------------------------------------------------
__global__ __launch_bounds__(256) void split_a(
    const float* __restrict__ in, _Float16* __restrict__ hi, _Float16* __restrict__ lo)
{
  const size_t i = (size_t)blockIdx.x * 256 + threadIdx.x;  // per 8 elems
  float4 a = ((const float4*)in)[i * 2];
  float4 b = ((const float4*)in)[i * 2 + 1];
  float v[8] = {a.x, a.y, a.z, a.w, b.x, b.y, b.z, b.w};
  half8 h, l;
  #pragma unroll
  for (int j = 0; j < 8; ++j) {
    half2s s = split1(v[j]);
    h[j] = s.h;
    l[j] = s.l;
  }
  *(half8*)(hi + i * 8) = h;
  *(half8*)(lo + i * 8) = l;
}

// ---------------------------------------------------------------------------
// split_pre_w: pre_w (24,512,64) f32 -> w2t_hi/lo (1536,512) fp16, transposed:
// w2t[cc][m] = pre_w[cc>>6][m][cc&63]
// ---------------------------------------------------------------------------
__global__ __launch_bounds__(256) void split_pre_w(
    const float* __restrict__ w, _Float16* __restrict__ hi, _Float16* __restrict__ lo)
{
  const int gid = blockIdx.x * 256 + threadIdx.x;  // 98304 total
  const int cc = gid >> 6;
  const int m0 = (gid & 63) << 3;
  const int g = cc >> 6, d = cc & 63;
  half8 h, l;
  #pragma unroll
  for (int j = 0; j < 8; ++j) {
    half2s s = split1(w[((size_t)g * M_ + m0 + j) * D_ + d]);
    h[j] = s.h;
    l[j] = s.l;
  }
  *(half8*)(hi + (size_t)cc * M_ + m0) = h;
  *(half8*)(lo + (size_t)cc * M_ + m0) = l;
}

// ---------------------------------------------------------------------------
// split_post_w: post_w (512,512) f32 -> pwt (512,512) fp16, pwt[cc][m] = post_w[m][cc]
// ---------------------------------------------------------------------------
__global__ __launch_bounds__(256) void split_post_w(
    const float* __restrict__ w, _Float16* __restrict__ hi)
{
  const int gid = blockIdx.x * 256 + threadIdx.x;  // 32768 total
  const int cc = gid >> 6;
  const int m0 = (gid & 63) << 3;
  half8 h;
  #pragma unroll
  for (int j = 0; j < 8; ++j) h[j] = (_Float16)w[(size_t)(m0 + j) * M_ + cc];
  *(half8*)(hi + (size_t)cc * M_ + m0) = h;
}

// ---------------------------------------------------------------------------
// qkv_mfma: C(32768 x 1536) = A(32768x512) x W^T-stored(1536x512), hi/lo split.
// THREE=true (q,k cols): 3-term product. THREE=false (v cols): 1-term.
// 128x128 tile, BK=32, 4 waves x (64x64), 32x32x16 f16 MFMA.
// Epilogue: +bias, split q,k to fp16 hi/lo; v to fp16.
// ---------------------------------------------------------------------------
template <bool THREE>
__global__ __launch_bounds__(256, 2) void qkv_mfma(
    const _Float16* __restrict__ Ahi, const _Float16* __restrict__ Alo,
    const _Float16* __restrict__ Whi, const _Float16* __restrict__ Wlo,
    const float* __restrict__ bias, int cb0,
    _Float16* __restrict__ qh, _Float16* __restrict__ ql,
    _Float16* __restrict__ kh, _Float16* __restrict__ kl,
    _Float16* __restrict__ vh)
{
  __shared__ _Float16 Ash[128 * 36];
  __shared__ _Float16 Bsh[128 * 36];
  __shared__ _Float16 Asl[THREE ? 128 * 36 : 8];
  __shared__ _Float16 Bsl[THREE ? 128 * 36 : 8];

  const int t = threadIdx.x;
  const int lane = t & 63, w = t >> 6;
  const int wr = w >> 1, wc = w & 1;
  const int lr = lane & 31, hh = lane >> 5;
  const int col0 = (cb0 + blockIdx.x) * 128;
  const int row0 = blockIdx.y * 128;

  const int sr = t >> 2;          // 0..63
  const int so = (t & 3) * 8;     // 0,8,16,24 (halves)

  f32x16 acc[2][2];
  #pragma unroll
  for (int i = 0; i < 2; ++i)
    #pragma unroll
    for (int j = 0; j < 2; ++j)
      #pragma unroll
      for (int r = 0; r < 16; ++r) acc[i][j][r] = 0.f;

  half8 rah[2], ral[2], rbh[2], rbl[2];
  #pragma unroll
  for (int i = 0; i < 2; ++i) {
    size_t ga = (size_t)(row0 + sr + i * 64) * M_ + so;
    size_t gb = (size_t)(col0 + sr + i * 64) * M_ + so;
    rah[i] = *(const half8*)(Ahi + ga);
    rbh[i] = *(const half8*)(Whi + gb);
    if (THREE) { ral[i] = *(const half8*)(Alo + ga); rbl[i] = *(const half8*)(Wlo + gb); }
  }

  for (int k0 = 0; k0 < M_; k0 += 32) {
    #pragma unroll
    for (int i = 0; i < 2; ++i) {
      int r = sr + i * 64;
      lds_st8(&Ash[r * 36 + so], rah[i]);
      lds_st8(&Bsh[r * 36 + so], rbh[i]);
      if (THREE) { lds_st8(&Asl[r * 36 + so], ral[i]); lds_st8(&Bsl[r * 36 + so], rbl[i]); }
    }
    __syncthreads();
    if (k0 + 32 < M_) {
      #pragma unroll
      for (int i = 0; i < 2; ++i) {
        size_t ga = (size_t)(row0 + sr + i * 64) * M_ + k0 + 32 + so;
        size_t gb = (size_t)(col0 + sr + i * 64) * M_ + k0 + 32 + so;
        rah[i] = *(const half8*)(Ahi + ga);
        rbh[i] = *(const half8*)(Whi + gb);
        if (THREE) { ral[i] = *(const half8*)(Alo + ga); rbl[i] = *(const half8*)(Wlo + gb); }
      }
    }
    #pragma unroll
    for (int c = 0; c < 2; ++c) {
      half8 ah[2], bh[2], al[2], bl[2];
      #pragma unroll
      for (int i = 0; i < 2; ++i) {
        const int ar = (wr * 64 + i * 32 + lr) * 36 + c * 16 + hh * 8;
        const int br = (wc * 64 + i * 32 + lr) * 36 + c * 16 + hh * 8;
        ah[i] = lds_ld8(&Ash[ar]);
        bh[i] = lds_ld8(&Bsh[br]);
        if (THREE) { al[i] = lds_ld8(&Asl[ar]); bl[i] = lds_ld8(&Bsl[br]); }
      }
      #pragma unroll
      for (int i = 0; i < 2; ++i)
        #pragma unroll
        for (int j = 0; j < 2; ++j) {
          acc[i][j] = MFMA32(ah[i], bh[j], acc[i][j]);
          if (THREE) {
            acc[i][j] = MFMA32(ah[i], bl[j], acc[i][j]);
            acc[i][j] = MFMA32(al[i], bh[j], acc[i][j]);
          }
        }
    }
    __syncthreads();
  }

  // epilogue: g uniform per (block,wc); t3 uniform per block
  #pragma unroll
  for (int j = 0; j < 2; ++j) {
    const int cc = col0 + wc * 64 + j * 32 + lr;
    const int g = cc >> 6;
    const int t3 = g >> 3, hd = g & 7;
    const int d = cc & 63;
    const float bs = bias[cc];
    #pragma unroll
    for (int i = 0; i < 2; ++i) {
      #pragma unroll
      for (int r = 0; r < 16; ++r) {
        const int rrow = row0 + wr * 64 + i * 32 + (r & 3) + 8 * (r >> 2) + 4 * hh;
        const float x = acc[i][j][r] + bs;
        const size_t base = ((size_t)hd * NR_ + rrow) * D_ + d;
        if (THREE) {
          half2s s = split1(x);
          if (t3 == 0) { qh[base] = s.h; ql[base] = s.l; }
          else         { kh[base] = s.h; kl[base] = s.l; }
        } else {
          vh[base] = (_Float16)x;
        }
      }
    }
  }
}

// ---------------------------------------------------------------------------
// Kernel: MFMA flash attention (validated round 2); output now fp16.
// ---------------------------------------------------------------------------
__global__ __launch_bounds__(256) void attn_mfma(
    const _Float16* __restrict__ qh, const _Float16* __restrict__ ql,
    const _Float16* __restrict__ kh, const _Float16* __restrict__ kl,
    const _Float16* __restrict__ vh,
    const float* __restrict__ mask,   // (1024, 1024)
    _Float16* __restrict__ outa)      // (32768, 512) fp16
{
  __shared__ _Float16 Khi[64 * 72];
  __shared__ _Float16 Klo[64 * 72];
  __shared__ _Float16 Vt [64 * 72];

  const int t    = threadIdx.x;
  const int lane = t & 63, w = t >> 6;
  const int lq   = lane & 31, hh = lane >> 5;
  const int qt = blockIdx.x;
  const int b  = blockIdx.y;
  const int hd = blockIdx.z;

  const int q_row = qt * 128 + w * 32 + lq;
  const size_t headoff = (size_t)hd * NR_ * D_ + (size_t)b * L_ * D_;

  const size_t qbase = headoff + (size_t)q_row * D_;
  half8 Qhc[4], Qlc[4];
  #pragma unroll
  for (int c = 0; c < 4; ++c) {
    Qhc[c] = *(const half8*)(qh + qbase + c * 16 + hh * 8);
    Qlc[c] = *(const half8*)(ql + qbase + c * 16 + hh * 8);
  }

  const _Float16* Kph = kh + headoff;
  const _Float16* Kpl = kl + headoff;
  const _Float16* Vp  = vh + headoff;
  const float*   mrow = mask + (size_t)q_row * L_;

  const int srow = t >> 2;
  const int soff = (t & 3) * 16;

  float m_i = -3.0e38f, l_i = 0.f;
  f32x16 O0, O1;
  #pragma unroll
  for (int i = 0; i < 16; ++i) { O0[i] = 0.f; O1[i] = 0.f; }

  for (int kt = 0; kt < 16; ++kt) {
    __syncthreads();
    const size_t goff = (size_t)(kt * 64 + srow) * D_ + soff;
    *(half8*)&Khi[srow * 72 + soff]     = *(const half8*)(Kph + goff);
    *(half8*)&Khi[srow * 72 + soff + 8] = *(const half8*)(Kph + goff + 8);
    *(half8*)&Klo[srow * 72 + soff]     = *(const half8*)(Kpl + goff);
    *(half8*)&Klo[srow * 72 + soff + 8] = *(const half8*)(Kpl + goff + 8);
    half8 va = *(const half8*)(Vp + goff);
    half8 vb = *(const half8*)(Vp + goff + 8);
    #pragma unroll
    for (int j = 0; j < 8; ++j) {
      Vt[(soff + j) * 72 + srow]     = va[j];
      Vt[(soff + 8 + j) * 72 + srow] = vb[j];
    }
    __syncthreads();

    f32x16 S[2];
    #pragma unroll
    for (int s2 = 0; s2 < 2; ++s2) {
      f32x16 acc;
      #pragma unroll
      for (int i = 0; i < 16; ++i) acc[i] = 0.f;
      #pragma unroll
      for (int c = 0; c < 4; ++c) {
        half8 ah = *(const half8*)&Khi[(s2 * 32 + lq) * 72 + c * 16 + hh * 8];
        half8 al = *(const half8*)&Klo[(s2 * 32 + lq) * 72 + c * 16 + hh * 8];
        acc = MFMA32(ah, Qhc[c], acc);
        acc = MFMA32(ah, Qlc[c], acc);
        acc = MFMA32(al, Qhc[c], acc);
      }
      S[s2] = acc;
    }

    #pragma unroll
    for (int s2 = 0; s2 < 2; ++s2)
      #pragma unroll
      for (int m = 0; m < 4; ++m) {
        float4 mv = *(const float4*)(mrow + kt * 64 + s2 * 32 + m * 8 + hh * 4);
        S[s2][4 * m + 0] += mv.x;
        S[s2][4 * m + 1] += mv.y;
        S[s2][4 * m + 2] += mv.z;
        S[s2][4 * m + 3] += mv.w;
      }

    float tmax = -3.0e38f;
    #pragma unroll
    for (int s2 = 0; s2 < 2; ++s2)
      #pragma unroll
      for (int r = 0; r < 16; ++r) tmax = fmaxf(tmax, S[s2][r]);
    tmax = fmaxf(tmax, __shfl_xor(tmax, 32, 64));

    float mn = fmaxf(m_i, tmax);
    float sc = __expf(m_i - mn);
    m_i = mn;
    float rs = 0.f;
    #pragma unroll
    for (int s2 = 0; s2 < 2; ++s2)
      #pragma unroll
      for (int r = 0; r < 16; ++r) {
        float e = __expf(S[s2][r] - mn);
        S[s2][r] = e;
        rs += e;
      }
    rs += __shfl_xor(rs, 32, 64);
    l_i = l_i * sc + rs;
    O0 = O0 * sc;
    O1 = O1 * sc;

    #pragma unroll
    for (int kc = 0; kc < 4; ++kc) {
      const int s2 = kc >> 1, a2 = kc & 1;
      unsigned x0 = pkh(S[s2][8 * a2 + 0], S[s2][8 * a2 + 1]);
      unsigned x1 = pkh(S[s2][8 * a2 + 2], S[s2][8 * a2 + 3]);
      unsigned y0 = pkh(S[s2][8 * a2 + 4], S[s2][8 * a2 + 5]);
      unsigned y1 = pkh(S[s2][8 * a2 + 6], S[s2][8 * a2 + 7]);
      uint2v r0 = __builtin_amdgcn_permlane32_swap(x0, y0, false, false);
      uint2v r1 = __builtin_amdgcn_permlane32_swap(x1, y1, false, false);
      uint4v wv;
      wv.x = r0.x; wv.y = r1.x; wv.z = r0.y; wv.w = r1.y;
      half8 pfrag = __builtin_bit_cast(half8, wv);
      O0 = MFMA32(*(const half8*)&Vt[lq * 72 + kc * 16 + hh * 8], pfrag, O0);
      O1 = MFMA32(*(const half8*)&Vt[(32 + lq) * 72 + kc * 16 + hh * 8], pfrag, O1);
    }
  }

  float inv = 1.0f / l_i;
  _Float16* orow = outa + ((size_t)b * L_ + q_row) * M_ + hd * 64;
  #pragma unroll
  for (int m = 0; m < 4; ++m) {
    half4 v0 = {(_Float16)(O0[4 * m + 0] * inv), (_Float16)(O0[4 * m + 1] * inv),
                (_Float16)(O0[4 * m + 2] * inv), (_Float16)(O0[4 * m + 3] * inv)};
    *(half4*)(orow + m * 8 + hh * 4) = v0;
    half4 v1 = {(_Float16)(O1[4 * m + 0] * inv), (_Float16)(O1[4 * m + 1] * inv),
                (_Float16)(O1[4 * m + 2] * inv), (_Float16)(O1[4 * m + 3] * inv)};
    *(half4*)(orow + 32 + m * 8 + hh * 4) = v1;
  }
}

// ---------------------------------------------------------------------------
// post_mfma: out(32768x512 f32) = attn_h(32768x512 f16) x pwt(512x512 f16) + b
// Same tile structure as qkv_mfma, 1-term.
// ---------------------------------------------------------------------------
__global__ __launch_bounds__(256, 2) void post_mfma(
    const _Float16* __restrict__ Ah, const _Float16* __restrict__ Wt,
    const float* __restrict__ bias, float* __restrict__ C)
{
  __shared__ _Float16 Ash[128 * 36];
  __shared__ _Float16 Bsh[128 * 36];

  const int t = threadIdx.x;
  const int lane = t & 63, w = t >> 6;
  const int wr = w >> 1, wc = w & 1;
  const int lr = lane & 31, hh = lane >> 5;
  const int col0 = blockIdx.x * 128;
  const int row0 = blockIdx.y * 128;

  const int sr = t >> 2;
  const int so = (t & 3) * 8;

  f32x16 acc[2][2];
  #pragma unroll
  for (int i = 0; i < 2; ++i)
    #pragma unroll
    for (int j = 0; j < 2; ++j)
      #pragma unroll
      for (int r = 0; r < 16; ++r) acc[i][j][r] = 0.f;

  half8 rah[2], rbh[2];
  #pragma unroll
  for (int i = 0; i < 2; ++i) {
    rah[i] = *(const half8*)(Ah + (size_t)(row0 + sr + i * 64) * M_ + so);
    rbh[i] = *(const half8*)(Wt + (size_t)(col0 + sr + i * 64) * M_ + so);
  }

  for (int k0 = 0; k0 < M_; k0 += 32) {
    #pragma unroll
    for (int i = 0; i < 2; ++i) {
      int r = sr + i * 64;
      lds_st8(&Ash[r * 36 + so], rah[i]);
      lds_st8(&Bsh[r * 36 + so], rbh[i]);
    }
    __syncthreads();
    if (k0 + 32 < M_) {
      #pragma unroll
      for (int i = 0; i < 2; ++i) {
        rah[i] = *(const half8*)(Ah + (size_t)(row0 + sr + i * 64) * M_ + k0 + 32 + so);
        rbh[i] = *(const half8*)(Wt + (size_t)(col0 + sr + i * 64) * M_ + k0 + 32 + so);
      }
    }
    #pragma unroll
    for (int c = 0; c < 2; ++c) {
      half8 ah[2], bh[2];
      #pragma unroll
      for (int i = 0; i < 2; ++i) {
        ah[i] = lds_ld8(&Ash[(wr * 64 + i * 32 + lr) * 36 + c * 16 + hh * 8]);
        bh[i] = lds_ld8(&Bsh[(wc * 64 + i * 32 + lr) * 36 + c * 16 + hh * 8]);
      }
      #pragma unroll
      for (int i = 0; i < 2; ++i)
        #pragma unroll
        for (int j = 0; j < 2; ++j)
          acc[i][j] = MFMA32(ah[i], bh[j], acc[i][j]);
    }
    __syncthreads();
  }

  #pragma unroll
  for (int j = 0; j < 2; ++j) {
    const int cc = col0 + wc * 64 + j * 32 + lr;
    const float bs = bias[cc];
    #pragma unroll
    for (int i = 0; i < 2; ++i)
      #pragma unroll
      for (int r = 0; r < 16; ++r) {
        const int rrow = row0 + wr * 64 + i * 32 + (r & 3) + 8 * (r >> 2) + 4 * hh;
        C[(size_t)rrow * M_ + cc] = acc[i][j][r] + bs;
      }
  }
}

extern "C" void kernel_launch(void* const* d_in, const int* in_sizes, int n_in,
                              void* d_out, int out_size, void* d_ws, size_t ws_size,
                              hipStream_t stream) {
  const float* inp    = (const float*)d_in[0];
  const float* mask   = (const float*)d_in[1];
  const float* pre_w  = (const float*)d_in[2];
  const float* pre_b  = (const float*)d_in[3];
  const float* post_w = (const float*)d_in[4];
  const float* post_b = (const float*)d_in[5];
  float* out = (float*)d_out;

  const size_t AE  = (size_t)NR_ * M_;        // 16,777,216 (2^24)
  const size_t HNE = (size_t)H_ * NR_ * D_;   // 16,777,216

  _Float16* a_hi   = (_Float16*)d_ws;         // aliased by attn_h after qkv
  _Float16* a_lo   = a_hi + AE;
  _Float16* w2t_hi = a_lo + AE;               // (1536,512)
  _Float16* w2t_lo = w2t_hi + (size_t)1536 * M_;
  _Float16* pwt    = w2t_lo + (size_t)1536 * M_;   // (512,512)
  _Float16* q_hi   = pwt + (size_t)M_ * M_;
  _Float16* q_lo   = q_hi + HNE;
  _Float16* k_hi   = q_lo + HNE;
  _Float16* k_lo   = k_hi + HNE;
  _Float16* v_h    = k_lo + HNE;
  _Float16* attn_h = a_hi;                    // reuse (a_hi dead after qkv_mfma)

  split_a<<<8192, 256, 0, stream>>>(inp, a_hi, a_lo);
  split_pre_w<<<384, 256, 0, stream>>>(pre_w, w2t_hi, w2t_lo);
  split_post_w<<<128, 256, 0, stream>>>(post_w, pwt);

  qkv_mfma<true><<<dim3(8, 256), 256, 0, stream>>>(
      a_hi, a_lo, w2t_hi, w2t_lo, pre_b, 0, q_hi, q_lo, k_hi, k_lo, v_h);
  qkv_mfma<false><<<dim3(4, 256), 256, 0, stream>>>(
      a_hi, a_lo, w2t_hi, w2t_lo, pre_b, 8, q_hi, q_lo, k_hi, k_lo, v_h);

  attn_mfma<<<dim3(8, 32, 8), 256, 0, stream>>>(q_hi, q_lo, k_hi, k_lo, v_h,
                                                mask, attn_h);

  post_mfma<<<dim3(4, 256), 256, 0, stream>>>(attn_h, pwt, post_b, out);
}

// Round 5
// 500.909 us; speedup vs baseline: 4.7829x; 1.0503x over previous
//
#include <hip/hip_runtime.h>

#define H_ 8
#define B_ 32
#define L_ 1024
#define D_ 64
#define M_ 512
#define NR_ 32768  // B_*L_
#define LOG2E 1.44269504088896340736f

typedef _Float16 half8 __attribute__((ext_vector_type(8)));
typedef _Float16 half4 __attribute__((ext_vector_type(4)));
typedef float f32x16 __attribute__((ext_vector_type(16)));
typedef unsigned int uint2v __attribute__((ext_vector_type(2)));
typedef unsigned int uint4v __attribute__((ext_vector_type(4)));

#define MFMA32(A, B, C) __builtin_amdgcn_mfma_f32_32x32x16_f16(A, B, C, 0, 0, 0)

static __device__ __forceinline__ unsigned pkh(float a, float b) {
  return __builtin_bit_cast(unsigned, __builtin_amdgcn_cvt_pkrtz(a, b));
}
// 8B-aligned LDS moves (row strides 36/68 halves are 8B- but not 16B-aligned)
static __device__ __forceinline__ half8 lds_ld8(const _Float16* p) {
  half4 a = *(const half4*)p;
  half4 b = *(const half4*)(p + 4);
  return __builtin_shufflevector(a, b, 0, 1, 2, 3, 4, 5, 6, 7);
}
static __device__ __forceinline__ void lds_st8(_Float16* p, half8 v) {
  *(half4*)p       = __builtin_shufflevector(v, v, 0, 1, 2, 3);
  *(half4*)(p + 4) = __builtin_shufflevector(v, v, 4, 5, 6, 7);
}
struct half2s { _Float16 h, l; };
static __device__ __forceinline__ half2s split1(float x) {
  half2s r;
  r.h = (_Float16)x;
  r.l = (_Float16)(x - (float)r.h);
  return r;
}

// ---------------------------------------------------------------------------
// split_a: inp (32768x512 f32) -> a_hi, a_lo fp16 (same layout)
// ---------------------------------------------------------------------------
__global__ __launch_bounds__(256) void split_a(
    const float* __restrict__ in, _Float16* __restrict__ hi, _Float16* __restrict__ lo)
{
  const size_t i = (size_t)blockIdx.x * 256 + threadIdx.x;  // per 8 elems
  float4 a = ((const float4*)in)[i * 2];
  float4 b = ((const float4*)in)[i * 2 + 1];
  float v[8] = {a.x, a.y, a.z, a.w, b.x, b.y, b.z, b.w};
  half8 h, l;
  #pragma unroll
  for (int j = 0; j < 8; ++j) {
    half2s s = split1(v[j]);
    h[j] = s.h;
    l[j] = s.l;
  }
  *(half8*)(hi + i * 8) = h;
  *(half8*)(lo + i * 8) = l;
}

// ---------------------------------------------------------------------------
// split_pre_w: pre_w (24,512,64) f32 -> w2t_hi/lo (1536,512) fp16 transposed
// ---------------------------------------------------------------------------
__global__ __launch_bounds__(256) void split_pre_w(
    const float* __restrict__ w, _Float16* __restrict__ hi, _Float16* __restrict__ lo)
{
  const int gid = blockIdx.x * 256 + threadIdx.x;  // 98304 total
  const int cc = gid >> 6;
  const int m0 = (gid & 63) << 3;
  const int g = cc >> 6, d = cc & 63;
  half8 h, l;
  #pragma unroll
  for (int j = 0; j < 8; ++j) {
    half2s s = split1(w[((size_t)g * M_ + m0 + j) * D_ + d]);
    h[j] = s.h;
    l[j] = s.l;
  }
  *(half8*)(hi + (size_t)cc * M_ + m0) = h;
  *(half8*)(lo + (size_t)cc * M_ + m0) = l;
}

// ---------------------------------------------------------------------------
// split_post_w: post_w (512,512) f32 -> pwt (512,512) fp16 transposed
// ---------------------------------------------------------------------------
__global__ __launch_bounds__(256) void split_post_w(
    const float* __restrict__ w, _Float16* __restrict__ hi)
{
  const int gid = blockIdx.x * 256 + threadIdx.x;  // 32768 total
  const int cc = gid >> 6;
  const int m0 = (gid & 63) << 3;
  half8 h;
  #pragma unroll
  for (int j = 0; j < 8; ++j) h[j] = (_Float16)w[(size_t)(m0 + j) * M_ + cc];
  *(half8*)(hi + (size_t)cc * M_ + m0) = h;
}

// ---------------------------------------------------------------------------
// scale_mask: mask2 = mask * log2(e)  (so attn can use exp2 directly)
// ---------------------------------------------------------------------------
__global__ __launch_bounds__(256) void scale_mask(
    const float* __restrict__ in, float* __restrict__ out)
{
  const size_t i = (size_t)blockIdx.x * 256 + threadIdx.x;  // per float4
  float4 v = ((const float4*)in)[i];
  float4 r = {v.x * LOG2E, v.y * LOG2E, v.z * LOG2E, v.w * LOG2E};
  ((float4*)out)[i] = r;
}

// ---------------------------------------------------------------------------
// qkv_mfma: C(32768 x 1536) = A x W^T-stored, fp16 hi/lo split GEMM.
// THREE=true (q,k): 3-term. THREE=false (v): 1-term.
// Q is additionally pre-scaled by log2(e) before the hi/lo split.
// ---------------------------------------------------------------------------
template <bool THREE>
__global__ __launch_bounds__(256, 2) void qkv_mfma(
    const _Float16* __restrict__ Ahi, const _Float16* __restrict__ Alo,
    const _Float16* __restrict__ Whi, const _Float16* __restrict__ Wlo,
    const float* __restrict__ bias, int cb0,
    _Float16* __restrict__ qh, _Float16* __restrict__ ql,
    _Float16* __restrict__ kh, _Float16* __restrict__ kl,
    _Float16* __restrict__ vh)
{
  __shared__ _Float16 Ash[128 * 36];
  __shared__ _Float16 Bsh[128 * 36];
  __shared__ _Float16 Asl[THREE ? 128 * 36 : 8];
  __shared__ _Float16 Bsl[THREE ? 128 * 36 : 8];

  const int t = threadIdx.x;
  const int lane = t & 63, w = t >> 6;
  const int wr = w >> 1, wc = w & 1;
  const int lr = lane & 31, hh = lane >> 5;
  const int col0 = (cb0 + blockIdx.x) * 128;
  const int row0 = blockIdx.y * 128;

  const int sr = t >> 2;
  const int so = (t & 3) * 8;

  f32x16 acc[2][2];
  #pragma unroll
  for (int i = 0; i < 2; ++i)
    #pragma unroll
    for (int j = 0; j < 2; ++j)
      #pragma unroll
      for (int r = 0; r < 16; ++r) acc[i][j][r] = 0.f;

  half8 rah[2], ral[2], rbh[2], rbl[2];
  #pragma unroll
  for (int i = 0; i < 2; ++i) {
    size_t ga = (size_t)(row0 + sr + i * 64) * M_ + so;
    size_t gb = (size_t)(col0 + sr + i * 64) * M_ + so;
    rah[i] = *(const half8*)(Ahi + ga);
    rbh[i] = *(const half8*)(Whi + gb);
    if (THREE) { ral[i] = *(const half8*)(Alo + ga); rbl[i] = *(const half8*)(Wlo + gb); }
  }

  for (int k0 = 0; k0 < M_; k0 += 32) {
    #pragma unroll
    for (int i = 0; i < 2; ++i) {
      int r = sr + i * 64;
      lds_st8(&Ash[r * 36 + so], rah[i]);
      lds_st8(&Bsh[r * 36 + so], rbh[i]);
      if (THREE) { lds_st8(&Asl[r * 36 + so], ral[i]); lds_st8(&Bsl[r * 36 + so], rbl[i]); }
    }
    __syncthreads();
    if (k0 + 32 < M_) {
      #pragma unroll
      for (int i = 0; i < 2; ++i) {
        size_t ga = (size_t)(row0 + sr + i * 64) * M_ + k0 + 32 + so;
        size_t gb = (size_t)(col0 + sr + i * 64) * M_ + k0 + 32 + so;
        rah[i] = *(const half8*)(Ahi + ga);
        rbh[i] = *(const half8*)(Whi + gb);
        if (THREE) { ral[i] = *(const half8*)(Alo + ga); rbl[i] = *(const half8*)(Wlo + gb); }
      }
    }
    #pragma unroll
    for (int c = 0; c < 2; ++c) {
      half8 ah[2], bh[2], al[2], bl[2];
      #pragma unroll
      for (int i = 0; i < 2; ++i) {
        const int ar = (wr * 64 + i * 32 + lr) * 36 + c * 16 + hh * 8;
        const int br = (wc * 64 + i * 32 + lr) * 36 + c * 16 + hh * 8;
        ah[i] = lds_ld8(&Ash[ar]);
        bh[i] = lds_ld8(&Bsh[br]);
        if (THREE) { al[i] = lds_ld8(&Asl[ar]); bl[i] = lds_ld8(&Bsl[br]); }
      }
      __builtin_amdgcn_s_setprio(1);
      #pragma unroll
      for (int i = 0; i < 2; ++i)
        #pragma unroll
        for (int j = 0; j < 2; ++j) {
          acc[i][j] = MFMA32(ah[i], bh[j], acc[i][j]);
          if (THREE) {
            acc[i][j] = MFMA32(ah[i], bl[j], acc[i][j]);
            acc[i][j] = MFMA32(al[i], bh[j], acc[i][j]);
          }
        }
      __builtin_amdgcn_s_setprio(0);
    }
    __syncthreads();
  }

  #pragma unroll
  for (int j = 0; j < 2; ++j) {
    const int cc = col0 + wc * 64 + j * 32 + lr;
    const int g = cc >> 6;
    const int t3 = g >> 3, hd = g & 7;
    const int d = cc & 63;
    const float bs = bias[cc];
    #pragma unroll
    for (int i = 0; i < 2; ++i) {
      #pragma unroll
      for (int r = 0; r < 16; ++r) {
        const int rrow = row0 + wr * 64 + i * 32 + (r & 3) + 8 * (r >> 2) + 4 * hh;
        const float x = acc[i][j][r] + bs;
        const size_t base = ((size_t)hd * NR_ + rrow) * D_ + d;
        if (THREE) {
          if (t3 == 0) {
            half2s s = split1(x * LOG2E);   // fold log2(e) into Q
            qh[base] = s.h; ql[base] = s.l;
          } else {
            half2s s = split1(x);
            kh[base] = s.h; kl[base] = s.l;
          }
        } else {
          vh[base] = (_Float16)x;
        }
      }
    }
  }
}

// ---------------------------------------------------------------------------
// attn_mfma v2: async double-buffered staging, 1 barrier/kt, LDS stride 68
// (51 KB -> 3 blocks/CU), qt pinned to XCD (mask L2), exp2 softmax, setprio.
// ---------------------------------------------------------------------------
__global__ __launch_bounds__(256) void attn_mfma(
    const _Float16* __restrict__ qh, const _Float16* __restrict__ ql,
    const _Float16* __restrict__ kh, const _Float16* __restrict__ kl,
    const _Float16* __restrict__ vh,
    const float* __restrict__ mask2,  // (1024,1024), pre-scaled by log2(e)
    _Float16* __restrict__ outa)      // (32768, 512) fp16
{
  constexpr int ST = 68;              // halves; 8B-aligned rows, 2-way banks max
  __shared__ _Float16 KhS[2][64 * ST];
  __shared__ _Float16 KlS[2][64 * ST];
  __shared__ _Float16 VtS[2][64 * ST];

  const int t    = threadIdx.x;
  const int lane = t & 63, w = t >> 6;
  const int lq   = lane & 31, hh = lane >> 5;
  const int id = blockIdx.x;          // 2048 linear
  const int qt = id & 7;              // pin qt per XCD -> mask slice L2-resident
  const int bh = id >> 3;
  const int b  = bh & 31;
  const int hd = bh >> 5;

  const int q_row = qt * 128 + w * 32 + lq;
  const size_t headoff = (size_t)hd * NR_ * D_ + (size_t)b * L_ * D_;

  const size_t qbase = headoff + (size_t)q_row * D_;
  half8 Qhc[4], Qlc[4];
  #pragma unroll
  for (int c = 0; c < 4; ++c) {
    Qhc[c] = *(const half8*)(qh + qbase + c * 16 + hh * 8);
    Qlc[c] = *(const half8*)(ql + qbase + c * 16 + hh * 8);
  }

  const _Float16* Kph = kh + headoff;
  const _Float16* Kpl = kl + headoff;
  const _Float16* Vp  = vh + headoff;
  const float*   mrow = mask2 + (size_t)q_row * L_;

  const int srow = t >> 2;            // 0..63
  const int soff = (t & 3) * 16;      // 0,16,32,48 halves

  float m_i = -3.0e38f, l_i = 0.f;
  f32x16 O0, O1;
  #pragma unroll
  for (int i = 0; i < 16; ++i) { O0[i] = 0.f; O1[i] = 0.f; }

  // staging registers (next tile in flight)
  half8 rkh0, rkh1, rkl0, rkl1, rv0, rv1;
  {
    const size_t goff = (size_t)srow * D_ + soff;   // kt = 0
    rkh0 = *(const half8*)(Kph + goff);
    rkh1 = *(const half8*)(Kph + goff + 8);
    rkl0 = *(const half8*)(Kpl + goff);
    rkl1 = *(const half8*)(Kpl + goff + 8);
    rv0  = *(const half8*)(Vp + goff);
    rv1  = *(const half8*)(Vp + goff + 8);
  }
  {
    _Float16* Kh = KhS[0];
    _Float16* Kl = KlS[0];
    _Float16* Vt = VtS[0];
    lds_st8(&Kh[srow * ST + soff],     rkh0);
    lds_st8(&Kh[srow * ST + soff + 8], rkh1);
    lds_st8(&Kl[srow * ST + soff],     rkl0);
    lds_st8(&Kl[srow * ST + soff + 8], rkl1);
    #pragma unroll
    for (int j = 0; j < 8; ++j) {
      Vt[(soff + j) * ST + srow]     = rv0[j];
      Vt[(soff + 8 + j) * ST + srow] = rv1[j];
    }
  }

  for (int kt = 0; kt < 16; ++kt) {
    const int cur = kt & 1;
    __syncthreads();   // buf[cur] complete

    // issue next-tile global loads (consumed at end-of-iteration LDS write)
    if (kt + 1 < 16) {
      const size_t goff = (size_t)((kt + 1) * 64 + srow) * D_ + soff;
      rkh0 = *(const half8*)(Kph + goff);
      rkh1 = *(const half8*)(Kph + goff + 8);
      rkl0 = *(const half8*)(Kpl + goff);
      rkl1 = *(const half8*)(Kpl + goff + 8);
      rv0  = *(const half8*)(Vp + goff);
      rv1  = *(const half8*)(Vp + goff + 8);
    }
    // issue current-tile mask loads (consumed after QK^T)
    float4 mc[8];
    #pragma unroll
    for (int m = 0; m < 8; ++m)
      mc[m] = *(const float4*)(mrow + kt * 64 + (m >> 2) * 32 + (m & 3) * 8 + hh * 4);

    const _Float16* Kh = KhS[cur];
    const _Float16* Kl = KlS[cur];
    const _Float16* Vt = VtS[cur];

    // ---- S^T = K . Q (3-term hi/lo), two 32-k subtiles ----
    f32x16 S[2];
    #pragma unroll
    for (int s2 = 0; s2 < 2; ++s2) {
      f32x16 acc;
      #pragma unroll
      for (int i = 0; i < 16; ++i) acc[i] = 0.f;
      #pragma unroll
      for (int c = 0; c < 4; ++c) {
        half8 ah = lds_ld8(&Kh[(s2 * 32 + lq) * ST + c * 16 + hh * 8]);
        half8 al = lds_ld8(&Kl[(s2 * 32 + lq) * ST + c * 16 + hh * 8]);
        __builtin_amdgcn_s_setprio(1);
        acc = MFMA32(ah, Qhc[c], acc);
        acc = MFMA32(ah, Qlc[c], acc);
        acc = MFMA32(al, Qhc[c], acc);
        __builtin_amdgcn_s_setprio(0);
      }
      S[s2] = acc;
    }

    // ---- + mask (log2 units); online softmax via exp2 ----
    #pragma unroll
    for (int s2 = 0; s2 < 2; ++s2)
      #pragma unroll
      for (int m = 0; m < 4; ++m) {
        float4 mv = mc[s2 * 4 + m];
        S[s2][4 * m + 0] += mv.x;
        S[s2][4 * m + 1] += mv.y;
        S[s2][4 * m + 2] += mv.z;
        S[s2][4 * m + 3] += mv.w;
      }

    float tmax = -3.0e38f;
    #pragma unroll
    for (int s2 = 0; s2 < 2; ++s2)
      #pragma unroll
      for (int r = 0; r < 16; ++r) tmax = fmaxf(tmax, S[s2][r]);
    tmax = fmaxf(tmax, __shfl_xor(tmax, 32, 64));

    float mn = fmaxf(m_i, tmax);
    float sc = exp2f(m_i - mn);
    m_i = mn;
    float rs = 0.f;
    #pragma unroll
    for (int s2 = 0; s2 < 2; ++s2)
      #pragma unroll
      for (int r = 0; r < 16; ++r) {
        float e = exp2f(S[s2][r] - mn);
        S[s2][r] = e;
        rs += e;
      }
    rs += __shfl_xor(rs, 32, 64);
    l_i = l_i * sc + rs;
    O0 = O0 * sc;
    O1 = O1 * sc;

    // ---- O^T += V^T . P^T ; P^T frags via cvt_pkrtz + permlane32_swap ----
    #pragma unroll
    for (int kc = 0; kc < 4; ++kc) {
      const int s2 = kc >> 1, a2 = kc & 1;
      unsigned x0 = pkh(S[s2][8 * a2 + 0], S[s2][8 * a2 + 1]);
      unsigned x1 = pkh(S[s2][8 * a2 + 2], S[s2][8 * a2 + 3]);
      unsigned y0 = pkh(S[s2][8 * a2 + 4], S[s2][8 * a2 + 5]);
      unsigned y1 = pkh(S[s2][8 * a2 + 6], S[s2][8 * a2 + 7]);
      uint2v r0 = __builtin_amdgcn_permlane32_swap(x0, y0, false, false);
      uint2v r1 = __builtin_amdgcn_permlane32_swap(x1, y1, false, false);
      uint4v wv;
      wv.x = r0.x; wv.y = r1.x; wv.z = r0.y; wv.w = r1.y;
      half8 pfrag = __builtin_bit_cast(half8, wv);
      half8 va = lds_ld8(&Vt[lq * ST + kc * 16 + hh * 8]);
      half8 vb = lds_ld8(&Vt[(32 + lq) * ST + kc * 16 + hh * 8]);
      __builtin_amdgcn_s_setprio(1);
      O0 = MFMA32(va, pfrag, O0);
      O1 = MFMA32(vb, pfrag, O1);
      __builtin_amdgcn_s_setprio(0);
    }

    // ---- write next tile into the other buffer ----
    if (kt + 1 < 16) {
      _Float16* Kh2 = KhS[cur ^ 1];
      _Float16* Kl2 = KlS[cur ^ 1];
      _Float16* Vt2 = VtS[cur ^ 1];
      lds_st8(&Kh2[srow * ST + soff],     rkh0);
      lds_st8(&Kh2[srow * ST + soff + 8], rkh1);
      lds_st8(&Kl2[srow * ST + soff],     rkl0);
      lds_st8(&Kl2[srow * ST + soff + 8], rkl1);
      #pragma unroll
      for (int j = 0; j < 8; ++j) {
        Vt2[(soff + j) * ST + srow]     = rv0[j];
        Vt2[(soff + 8 + j) * ST + srow] = rv1[j];
      }
    }
  }

  float inv = 1.0f / l_i;
  _Float16* orow = outa + ((size_t)b * L_ + q_row) * M_ + hd * 64;
  #pragma unroll
  for (int m = 0; m < 4; ++m) {
    half4 v0 = {(_Float16)(O0[4 * m + 0] * inv), (_Float16)(O0[4 * m + 1] * inv),
                (_Float16)(O0[4 * m + 2] * inv), (_Float16)(O0[4 * m + 3] * inv)};
    *(half4*)(orow + m * 8 + hh * 4) = v0;
    half4 v1 = {(_Float16)(O1[4 * m + 0] * inv), (_Float16)(O1[4 * m + 1] * inv),
                (_Float16)(O1[4 * m + 2] * inv), (_Float16)(O1[4 * m + 3] * inv)};
    *(half4*)(orow + 32 + m * 8 + hh * 4) = v1;
  }
}

// ---------------------------------------------------------------------------
// post_mfma: out(32768x512 f32) = attn_h(f16) x pwt(f16) + bias
// ---------------------------------------------------------------------------
__global__ __launch_bounds__(256, 2) void post_mfma(
    const _Float16* __restrict__ Ah, const _Float16* __restrict__ Wt,
    const float* __restrict__ bias, float* __restrict__ C)
{
  __shared__ _Float16 Ash[128 * 36];
  __shared__ _Float16 Bsh[128 * 36];

  const int t = threadIdx.x;
  const int lane = t & 63, w = t >> 6;
  const int wr = w >> 1, wc = w & 1;
  const int lr = lane & 31, hh = lane >> 5;
  const int col0 = blockIdx.x * 128;
  const int row0 = blockIdx.y * 128;

  const int sr = t >> 2;
  const int so = (t & 3) * 8;

  f32x16 acc[2][2];
  #pragma unroll
  for (int i = 0; i < 2; ++i)
    #pragma unroll
    for (int j = 0; j < 2; ++j)
      #pragma unroll
      for (int r = 0; r < 16; ++r) acc[i][j][r] = 0.f;

  half8 rah[2], rbh[2];
  #pragma unroll
  for (int i = 0; i < 2; ++i) {
    rah[i] = *(const half8*)(Ah + (size_t)(row0 + sr + i * 64) * M_ + so);
    rbh[i] = *(const half8*)(Wt + (size_t)(col0 + sr + i * 64) * M_ + so);
  }

  for (int k0 = 0; k0 < M_; k0 += 32) {
    #pragma unroll
    for (int i = 0; i < 2; ++i) {
      int r = sr + i * 64;
      lds_st8(&Ash[r * 36 + so], rah[i]);
      lds_st8(&Bsh[r * 36 + so], rbh[i]);
    }
    __syncthreads();
    if (k0 + 32 < M_) {
      #pragma unroll
      for (int i = 0; i < 2; ++i) {
        rah[i] = *(const half8*)(Ah + (size_t)(row0 + sr + i * 64) * M_ + k0 + 32 + so);
        rbh[i] = *(const half8*)(Wt + (size_t)(col0 + sr + i * 64) * M_ + k0 + 32 + so);
      }
    }
    #pragma unroll
    for (int c = 0; c < 2; ++c) {
      half8 ah[2], bh[2];
      #pragma unroll
      for (int i = 0; i < 2; ++i) {
        ah[i] = lds_ld8(&Ash[(wr * 64 + i * 32 + lr) * 36 + c * 16 + hh * 8]);
        bh[i] = lds_ld8(&Bsh[(wc * 64 + i * 32 + lr) * 36 + c * 16 + hh * 8]);
      }
      __builtin_amdgcn_s_setprio(1);
      #pragma unroll
      for (int i = 0; i < 2; ++i)
        #pragma unroll
        for (int j = 0; j < 2; ++j)
          acc[i][j] = MFMA32(ah[i], bh[j], acc[i][j]);
      __builtin_amdgcn_s_setprio(0);
    }
    __syncthreads();
  }

  #pragma unroll
  for (int j = 0; j < 2; ++j) {
    const int cc = col0 + wc * 64 + j * 32 + lr;
    const float bs = bias[cc];
    #pragma unroll
    for (int i = 0; i < 2; ++i)
      #pragma unroll
      for (int r = 0; r < 16; ++r) {
        const int rrow = row0 + wr * 64 + i * 32 + (r & 3) + 8 * (r >> 2) + 4 * hh;
        C[(size_t)rrow * M_ + cc] = acc[i][j][r] + bs;
      }
  }
}

extern "C" void kernel_launch(void* const* d_in, const int* in_sizes, int n_in,
                              void* d_out, int out_size, void* d_ws, size_t ws_size,
                              hipStream_t stream) {
  const float* inp    = (const float*)d_in[0];
  const float* mask   = (const float*)d_in[1];
  const float* pre_w  = (const float*)d_in[2];
  const float* pre_b  = (const float*)d_in[3];
  const float* post_w = (const float*)d_in[4];
  const float* post_b = (const float*)d_in[5];
  float* out = (float*)d_out;

  const size_t AE  = (size_t)NR_ * M_;        // 16,777,216
  const size_t HNE = (size_t)H_ * NR_ * D_;   // 16,777,216

  _Float16* a_hi   = (_Float16*)d_ws;         // aliased by attn_h after qkv
  _Float16* a_lo   = a_hi + AE;
  _Float16* w2t_hi = a_lo + AE;               // (1536,512)
  _Float16* w2t_lo = w2t_hi + (size_t)1536 * M_;
  _Float16* pwt    = w2t_lo + (size_t)1536 * M_;   // (512,512)
  _Float16* q_hi   = pwt + (size_t)M_ * M_;
  _Float16* q_lo   = q_hi + HNE;
  _Float16* k_hi   = q_lo + HNE;
  _Float16* k_lo   = k_hi + HNE;
  _Float16* v_h    = k_lo + HNE;
  float*    mask2  = (float*)(v_h + HNE);     // (1024,1024) f32
  _Float16* attn_h = a_hi;                    // reuse (a_hi dead after qkv)

  split_a<<<8192, 256, 0, stream>>>(inp, a_hi, a_lo);
  split_pre_w<<<384, 256, 0, stream>>>(pre_w, w2t_hi, w2t_lo);
  split_post_w<<<128, 256, 0, stream>>>(post_w, pwt);
  scale_mask<<<1024, 256, 0, stream>>>(mask, mask2);

  qkv_mfma<true><<<dim3(8, 256), 256, 0, stream>>>(
      a_hi, a_lo, w2t_hi, w2t_lo, pre_b, 0, q_hi, q_lo, k_hi, k_lo, v_h);
  qkv_mfma<false><<<dim3(4, 256), 256, 0, stream>>>(
      a_hi, a_lo, w2t_hi, w2t_lo, pre_b, 8, q_hi, q_lo, k_hi, k_lo, v_h);

  attn_mfma<<<2048, 256, 0, stream>>>(q_hi, q_lo, k_hi, k_lo, v_h,
                                      mask2, attn_h);

  post_mfma<<<dim3(4, 256), 256, 0, stream>>>(attn_h, pwt, post_b, out);
}

// Round 6
// 497.268 us; speedup vs baseline: 4.8179x; 1.0073x over previous
//
#include <hip/hip_runtime.h>

#define H_ 8
#define B_ 32
#define L_ 1024
#define D_ 64
#define M_ 512
#define NR_ 32768  // B_*L_
#define LOG2E 1.44269504088896340736f

typedef _Float16 half8 __attribute__((ext_vector_type(8)));
typedef _Float16 half4 __attribute__((ext_vector_type(4)));
typedef float f32x16 __attribute__((ext_vector_type(16)));
typedef unsigned int uint2v __attribute__((ext_vector_type(2)));
typedef unsigned int uint4v __attribute__((ext_vector_type(4)));

#define MFMA32(A, B, C) __builtin_amdgcn_mfma_f32_32x32x16_f16(A, B, C, 0, 0, 0)

static __device__ __forceinline__ unsigned pkh(float a, float b) {
  return __builtin_bit_cast(unsigned, __builtin_amdgcn_cvt_pkrtz(a, b));
}
// 8B-aligned LDS moves (row strides 36/68 halves are 8B- but not 16B-aligned)
static __device__ __forceinline__ half8 lds_ld8(const _Float16* p) {
  half4 a = *(const half4*)p;
  half4 b = *(const half4*)(p + 4);
  return __builtin_shufflevector(a, b, 0, 1, 2, 3, 4, 5, 6, 7);
}
static __device__ __forceinline__ void lds_st8(_Float16* p, half8 v) {
  *(half4*)p       = __builtin_shufflevector(v, v, 0, 1, 2, 3);
  *(half4*)(p + 4) = __builtin_shufflevector(v, v, 4, 5, 6, 7);
}
struct half2s { _Float16 h, l; };
static __device__ __forceinline__ half2s split1(float x) {
  half2s r;
  r.h = (_Float16)x;
  r.l = (_Float16)(x - (float)r.h);
  return r;
}

// ---------------------------------------------------------------------------
// split_a: inp (32768x512 f32) -> a_hi, a_lo fp16 (same layout)
// ---------------------------------------------------------------------------
__global__ __launch_bounds__(256) void split_a(
    const float* __restrict__ in, _Float16* __restrict__ hi, _Float16* __restrict__ lo)
{
  const size_t i = (size_t)blockIdx.x * 256 + threadIdx.x;  // per 8 elems
  float4 a = ((const float4*)in)[i * 2];
  float4 b = ((const float4*)in)[i * 2 + 1];
  float v[8] = {a.x, a.y, a.z, a.w, b.x, b.y, b.z, b.w};
  half8 h, l;
  #pragma unroll
  for (int j = 0; j < 8; ++j) {
    half2s s = split1(v[j]);
    h[j] = s.h;
    l[j] = s.l;
  }
  *(half8*)(hi + i * 8) = h;
  *(half8*)(lo + i * 8) = l;
}

// ---------------------------------------------------------------------------
// split_pre_w: pre_w (24,512,64) f32 -> w2t_hi/lo (1536,512) fp16 transposed
// ---------------------------------------------------------------------------
__global__ __launch_bounds__(256) void split_pre_w(
    const float* __restrict__ w, _Float16* __restrict__ hi, _Float16* __restrict__ lo)
{
  const int gid = blockIdx.x * 256 + threadIdx.x;  // 98304 total
  const int cc = gid >> 6;
  const int m0 = (gid & 63) << 3;
  const int g = cc >> 6, d = cc & 63;
  half8 h, l;
  #pragma unroll
  for (int j = 0; j < 8; ++j) {
    half2s s = split1(w[((size_t)g * M_ + m0 + j) * D_ + d]);
    h[j] = s.h;
    l[j] = s.l;
  }
  *(half8*)(hi + (size_t)cc * M_ + m0) = h;
  *(half8*)(lo + (size_t)cc * M_ + m0) = l;
}

// ---------------------------------------------------------------------------
// split_post_w: post_w (512,512) f32 -> pwt (512,512) fp16 transposed
// ---------------------------------------------------------------------------
__global__ __launch_bounds__(256) void split_post_w(
    const float* __restrict__ w, _Float16* __restrict__ hi)
{
  const int gid = blockIdx.x * 256 + threadIdx.x;  // 32768 total
  const int cc = gid >> 6;
  const int m0 = (gid & 63) << 3;
  half8 h;
  #pragma unroll
  for (int j = 0; j < 8; ++j) h[j] = (_Float16)w[(size_t)(m0 + j) * M_ + cc];
  *(half8*)(hi + (size_t)cc * M_ + m0) = h;
}

// ---------------------------------------------------------------------------
// scale_mask: mask2 = mask * log2(e)  (so attn can use exp2 directly)
// ---------------------------------------------------------------------------
__global__ __launch_bounds__(256) void scale_mask(
    const float* __restrict__ in, float* __restrict__ out)
{
  const size_t i = (size_t)blockIdx.x * 256 + threadIdx.x;  // per float4
  float4 v = ((const float4*)in)[i];
  float4 r = {v.x * LOG2E, v.y * LOG2E, v.z * LOG2E, v.w * LOG2E};
  ((float4*)out)[i] = r;
}

// ---------------------------------------------------------------------------
// qkv_mfma: C(32768 x 1536) = A x W^T-stored, fp16 hi/lo split GEMM.
// THREE=true (q,k): 3-term. THREE=false (v): 1-term.
// Q is additionally pre-scaled by log2(e) before the hi/lo split.
// ---------------------------------------------------------------------------
template <bool THREE>
__global__ __launch_bounds__(256, 2) void qkv_mfma(
    const _Float16* __restrict__ Ahi, const _Float16* __restrict__ Alo,
    const _Float16* __restrict__ Whi, const _Float16* __restrict__ Wlo,
    const float* __restrict__ bias, int cb0,
    _Float16* __restrict__ qh, _Float16* __restrict__ ql,
    _Float16* __restrict__ kh, _Float16* __restrict__ kl,
    _Float16* __restrict__ vh)
{
  __shared__ _Float16 Ash[128 * 36];
  __shared__ _Float16 Bsh[128 * 36];
  __shared__ _Float16 Asl[THREE ? 128 * 36 : 8];
  __shared__ _Float16 Bsl[THREE ? 128 * 36 : 8];

  const int t = threadIdx.x;
  const int lane = t & 63, w = t >> 6;
  const int wr = w >> 1, wc = w & 1;
  const int lr = lane & 31, hh = lane >> 5;
  const int col0 = (cb0 + blockIdx.x) * 128;
  const int row0 = blockIdx.y * 128;

  const int sr = t >> 2;
  const int so = (t & 3) * 8;

  f32x16 acc[2][2];
  #pragma unroll
  for (int i = 0; i < 2; ++i)
    #pragma unroll
    for (int j = 0; j < 2; ++j)
      #pragma unroll
      for (int r = 0; r < 16; ++r) acc[i][j][r] = 0.f;

  half8 rah[2], ral[2], rbh[2], rbl[2];
  #pragma unroll
  for (int i = 0; i < 2; ++i) {
    size_t ga = (size_t)(row0 + sr + i * 64) * M_ + so;
    size_t gb = (size_t)(col0 + sr + i * 64) * M_ + so;
    rah[i] = *(const half8*)(Ahi + ga);
    rbh[i] = *(const half8*)(Whi + gb);
    if (THREE) { ral[i] = *(const half8*)(Alo + ga); rbl[i] = *(const half8*)(Wlo + gb); }
  }

  for (int k0 = 0; k0 < M_; k0 += 32) {
    #pragma unroll
    for (int i = 0; i < 2; ++i) {
      int r = sr + i * 64;
      lds_st8(&Ash[r * 36 + so], rah[i]);
      lds_st8(&Bsh[r * 36 + so], rbh[i]);
      if (THREE) { lds_st8(&Asl[r * 36 + so], ral[i]); lds_st8(&Bsl[r * 36 + so], rbl[i]); }
    }
    __syncthreads();
    if (k0 + 32 < M_) {
      #pragma unroll
      for (int i = 0; i < 2; ++i) {
        size_t ga = (size_t)(row0 + sr + i * 64) * M_ + k0 + 32 + so;
        size_t gb = (size_t)(col0 + sr + i * 64) * M_ + k0 + 32 + so;
        rah[i] = *(const half8*)(Ahi + ga);
        rbh[i] = *(const half8*)(Whi + gb);
        if (THREE) { ral[i] = *(const half8*)(Alo + ga); rbl[i] = *(const half8*)(Wlo + gb); }
      }
    }
    #pragma unroll
    for (int c = 0; c < 2; ++c) {
      half8 ah[2], bh[2], al[2], bl[2];
      #pragma unroll
      for (int i = 0; i < 2; ++i) {
        const int ar = (wr * 64 + i * 32 + lr) * 36 + c * 16 + hh * 8;
        const int br = (wc * 64 + i * 32 + lr) * 36 + c * 16 + hh * 8;
        ah[i] = lds_ld8(&Ash[ar]);
        bh[i] = lds_ld8(&Bsh[br]);
        if (THREE) { al[i] = lds_ld8(&Asl[ar]); bl[i] = lds_ld8(&Bsl[br]); }
      }
      __builtin_amdgcn_s_setprio(1);
      #pragma unroll
      for (int i = 0; i < 2; ++i)
        #pragma unroll
        for (int j = 0; j < 2; ++j) {
          acc[i][j] = MFMA32(ah[i], bh[j], acc[i][j]);
          if (THREE) {
            acc[i][j] = MFMA32(ah[i], bl[j], acc[i][j]);
            acc[i][j] = MFMA32(al[i], bh[j], acc[i][j]);
          }
        }
      __builtin_amdgcn_s_setprio(0);
    }
    __syncthreads();
  }

  #pragma unroll
  for (int j = 0; j < 2; ++j) {
    const int cc = col0 + wc * 64 + j * 32 + lr;
    const int g = cc >> 6;
    const int t3 = g >> 3, hd = g & 7;
    const int d = cc & 63;
    const float bs = bias[cc];
    #pragma unroll
    for (int i = 0; i < 2; ++i) {
      #pragma unroll
      for (int r = 0; r < 16; ++r) {
        const int rrow = row0 + wr * 64 + i * 32 + (r & 3) + 8 * (r >> 2) + 4 * hh;
        const float x = acc[i][j][r] + bs;
        const size_t base = ((size_t)hd * NR_ + rrow) * D_ + d;
        if (THREE) {
          if (t3 == 0) {
            half2s s = split1(x * LOG2E);   // fold log2(e) into Q
            qh[base] = s.h; ql[base] = s.l;
          } else {
            half2s s = split1(x);
            kh[base] = s.h; kl[base] = s.l;
          }
        } else {
          vh[base] = (_Float16)x;
        }
      }
    }
  }
}

// ---------------------------------------------------------------------------
// attn_mfma v3: + mask double-buffer prefetch (issued ~1 kt early, covers HBM
// latency), defer-max (skip O rescale while tile max stays within 8 log2
// units of running max; P <= 2^8 safe in fp16), max3-friendly reductions.
// ---------------------------------------------------------------------------
__global__ __launch_bounds__(256) void attn_mfma(
    const _Float16* __restrict__ qh, const _Float16* __restrict__ ql,
    const _Float16* __restrict__ kh, const _Float16* __restrict__ kl,
    const _Float16* __restrict__ vh,
    const float* __restrict__ mask2,  // (1024,1024), pre-scaled by log2(e)
    _Float16* __restrict__ outa)      // (32768, 512) fp16
{
  constexpr int ST = 68;              // halves; 8B-aligned rows, 2-way banks max
  __shared__ _Float16 KhS[2][64 * ST];
  __shared__ _Float16 KlS[2][64 * ST];
  __shared__ _Float16 VtS[2][64 * ST];

  const int t    = threadIdx.x;
  const int lane = t & 63, w = t >> 6;
  const int lq   = lane & 31, hh = lane >> 5;
  const int id = blockIdx.x;          // 2048 linear
  const int qt = id & 7;
  const int bh = id >> 3;
  const int b  = bh & 31;
  const int hd = bh >> 5;

  const int q_row = qt * 128 + w * 32 + lq;
  const size_t headoff = (size_t)hd * NR_ * D_ + (size_t)b * L_ * D_;

  const size_t qbase = headoff + (size_t)q_row * D_;
  half8 Qhc[4], Qlc[4];
  #pragma unroll
  for (int c = 0; c < 4; ++c) {
    Qhc[c] = *(const half8*)(qh + qbase + c * 16 + hh * 8);
    Qlc[c] = *(const half8*)(ql + qbase + c * 16 + hh * 8);
  }

  const _Float16* Kph = kh + headoff;
  const _Float16* Kpl = kl + headoff;
  const _Float16* Vp  = vh + headoff;
  const float*   mrow = mask2 + (size_t)q_row * L_;

  const int srow = t >> 2;            // 0..63
  const int soff = (t & 3) * 16;      // 0,16,32,48 halves

  float m_i = -3.0e38f, l_i = 0.f;
  f32x16 O0, O1;
  #pragma unroll
  for (int i = 0; i < 16; ++i) { O0[i] = 0.f; O1[i] = 0.f; }

  // staging registers (next K/V tile in flight)
  half8 rkh0, rkh1, rkl0, rkl1, rv0, rv1;
  {
    const size_t goff = (size_t)srow * D_ + soff;   // kt = 0
    rkh0 = *(const half8*)(Kph + goff);
    rkh1 = *(const half8*)(Kph + goff + 8);
    rkl0 = *(const half8*)(Kpl + goff);
    rkl1 = *(const half8*)(Kpl + goff + 8);
    rv0  = *(const half8*)(Vp + goff);
    rv1  = *(const half8*)(Vp + goff + 8);
  }
  // mask prefetch for kt = 0
  float4 mc[8];
  #pragma unroll
  for (int m = 0; m < 8; ++m)
    mc[m] = *(const float4*)(mrow + (m >> 2) * 32 + (m & 3) * 8 + hh * 4);

  {
    _Float16* Kh = KhS[0];
    _Float16* Kl = KlS[0];
    _Float16* Vt = VtS[0];
    lds_st8(&Kh[srow * ST + soff],     rkh0);
    lds_st8(&Kh[srow * ST + soff + 8], rkh1);
    lds_st8(&Kl[srow * ST + soff],     rkl0);
    lds_st8(&Kl[srow * ST + soff + 8], rkl1);
    #pragma unroll
    for (int j = 0; j < 8; ++j) {
      Vt[(soff + j) * ST + srow]     = rv0[j];
      Vt[(soff + 8 + j) * ST + srow] = rv1[j];
    }
  }

  for (int kt = 0; kt < 16; ++kt) {
    const int cur = kt & 1;
    __syncthreads();   // buf[cur] complete

    // issue next-tile global loads (K/V consumed at end-of-iter LDS write;
    // mask consumed in NEXT iteration's softmax -> ~full kt of latency cover)
    float4 mnx[8];
    if (kt + 1 < 16) {
      const size_t goff = (size_t)((kt + 1) * 64 + srow) * D_ + soff;
      rkh0 = *(const half8*)(Kph + goff);
      rkh1 = *(const half8*)(Kph + goff + 8);
      rkl0 = *(const half8*)(Kpl + goff);
      rkl1 = *(const half8*)(Kpl + goff + 8);
      rv0  = *(const half8*)(Vp + goff);
      rv1  = *(const half8*)(Vp + goff + 8);
      #pragma unroll
      for (int m = 0; m < 8; ++m)
        mnx[m] = *(const float4*)(mrow + (kt + 1) * 64 + (m >> 2) * 32 + (m & 3) * 8 + hh * 4);
    }

    const _Float16* Kh = KhS[cur];
    const _Float16* Kl = KlS[cur];
    const _Float16* Vt = VtS[cur];

    // ---- S^T = K . Q (3-term hi/lo), two 32-k subtiles ----
    f32x16 S[2];
    #pragma unroll
    for (int s2 = 0; s2 < 2; ++s2) {
      f32x16 acc;
      #pragma unroll
      for (int i = 0; i < 16; ++i) acc[i] = 0.f;
      #pragma unroll
      for (int c = 0; c < 4; ++c) {
        half8 ah = lds_ld8(&Kh[(s2 * 32 + lq) * ST + c * 16 + hh * 8]);
        half8 al = lds_ld8(&Kl[(s2 * 32 + lq) * ST + c * 16 + hh * 8]);
        __builtin_amdgcn_s_setprio(1);
        acc = MFMA32(ah, Qhc[c], acc);
        acc = MFMA32(ah, Qlc[c], acc);
        acc = MFMA32(al, Qhc[c], acc);
        __builtin_amdgcn_s_setprio(0);
      }
      S[s2] = acc;
    }

    // ---- + mask (log2 units) ----
    #pragma unroll
    for (int s2 = 0; s2 < 2; ++s2)
      #pragma unroll
      for (int m = 0; m < 4; ++m) {
        float4 mv = mc[s2 * 4 + m];
        S[s2][4 * m + 0] += mv.x;
        S[s2][4 * m + 1] += mv.y;
        S[s2][4 * m + 2] += mv.z;
        S[s2][4 * m + 3] += mv.w;
      }

    // ---- tile max (max3-friendly tree) ----
    float pm[8];
    #pragma unroll
    for (int g4 = 0; g4 < 8; ++g4) {
      const int s2 = g4 >> 2, m = g4 & 3;
      pm[g4] = fmaxf(fmaxf(S[s2][4 * m + 0], S[s2][4 * m + 1]),
                     fmaxf(S[s2][4 * m + 2], S[s2][4 * m + 3]));
    }
    float tmax = fmaxf(fmaxf(fmaxf(pm[0], pm[1]), fmaxf(pm[2], pm[3])),
                       fmaxf(fmaxf(pm[4], pm[5]), fmaxf(pm[6], pm[7])));
    tmax = fmaxf(tmax, __shfl_xor(tmax, 32, 64));

    // ---- defer-max: only rescale when the tile max grows past m_i + 8 ----
    if (!__all(tmax - m_i <= 8.0f)) {
      float mn = fmaxf(m_i, tmax);
      float sc = exp2f(m_i - mn);
      m_i = mn;
      l_i *= sc;
      O0 = O0 * sc;
      O1 = O1 * sc;
    }

    float rs = 0.f;
    #pragma unroll
    for (int s2 = 0; s2 < 2; ++s2)
      #pragma unroll
      for (int r = 0; r < 16; ++r) {
        float e = exp2f(S[s2][r] - m_i);
        S[s2][r] = e;
        rs += e;
      }
    rs += __shfl_xor(rs, 32, 64);
    l_i += rs;

    // ---- O^T += V^T . P^T ; P^T frags via cvt_pkrtz + permlane32_swap ----
    #pragma unroll
    for (int kc = 0; kc < 4; ++kc) {
      const int s2 = kc >> 1, a2 = kc & 1;
      unsigned x0 = pkh(S[s2][8 * a2 + 0], S[s2][8 * a2 + 1]);
      unsigned x1 = pkh(S[s2][8 * a2 + 2], S[s2][8 * a2 + 3]);
      unsigned y0 = pkh(S[s2][8 * a2 + 4], S[s2][8 * a2 + 5]);
      unsigned y1 = pkh(S[s2][8 * a2 + 6], S[s2][8 * a2 + 7]);
      uint2v r0 = __builtin_amdgcn_permlane32_swap(x0, y0, false, false);
      uint2v r1 = __builtin_amdgcn_permlane32_swap(x1, y1, false, false);
      uint4v wv;
      wv.x = r0.x; wv.y = r1.x; wv.z = r0.y; wv.w = r1.y;
      half8 pfrag = __builtin_bit_cast(half8, wv);
      half8 va = lds_ld8(&Vt[lq * ST + kc * 16 + hh * 8]);
      half8 vb = lds_ld8(&Vt[(32 + lq) * ST + kc * 16 + hh * 8]);
      __builtin_amdgcn_s_setprio(1);
      O0 = MFMA32(va, pfrag, O0);
      O1 = MFMA32(vb, pfrag, O1);
      __builtin_amdgcn_s_setprio(0);
    }

    // ---- write next tile into the other buffer; rotate mask regs ----
    if (kt + 1 < 16) {
      _Float16* Kh2 = KhS[cur ^ 1];
      _Float16* Kl2 = KlS[cur ^ 1];
      _Float16* Vt2 = VtS[cur ^ 1];
      lds_st8(&Kh2[srow * ST + soff],     rkh0);
      lds_st8(&Kh2[srow * ST + soff + 8], rkh1);
      lds_st8(&Kl2[srow * ST + soff],     rkl0);
      lds_st8(&Kl2[srow * ST + soff + 8], rkl1);
      #pragma unroll
      for (int j = 0; j < 8; ++j) {
        Vt2[(soff + j) * ST + srow]     = rv0[j];
        Vt2[(soff + 8 + j) * ST + srow] = rv1[j];
      }
      #pragma unroll
      for (int m = 0; m < 8; ++m) mc[m] = mnx[m];
    }
  }

  float inv = 1.0f / l_i;
  _Float16* orow = outa + ((size_t)b * L_ + q_row) * M_ + hd * 64;
  #pragma unroll
  for (int m = 0; m < 4; ++m) {
    half4 v0 = {(_Float16)(O0[4 * m + 0] * inv), (_Float16)(O0[4 * m + 1] * inv),
                (_Float16)(O0[4 * m + 2] * inv), (_Float16)(O0[4 * m + 3] * inv)};
    *(half4*)(orow + m * 8 + hh * 4) = v0;
    half4 v1 = {(_Float16)(O1[4 * m + 0] * inv), (_Float16)(O1[4 * m + 1] * inv),
                (_Float16)(O1[4 * m + 2] * inv), (_Float16)(O1[4 * m + 3] * inv)};
    *(half4*)(orow + 32 + m * 8 + hh * 4) = v1;
  }
}

// ---------------------------------------------------------------------------
// post_mfma: out(32768x512 f32) = attn_h(f16) x pwt(f16) + bias
// ---------------------------------------------------------------------------
__global__ __launch_bounds__(256, 2) void post_mfma(
    const _Float16* __restrict__ Ah, const _Float16* __restrict__ Wt,
    const float* __restrict__ bias, float* __restrict__ C)
{
  __shared__ _Float16 Ash[128 * 36];
  __shared__ _Float16 Bsh[128 * 36];

  const int t = threadIdx.x;
  const int lane = t & 63, w = t >> 6;
  const int wr = w >> 1, wc = w & 1;
  const int lr = lane & 31, hh = lane >> 5;
  const int col0 = blockIdx.x * 128;
  const int row0 = blockIdx.y * 128;

  const int sr = t >> 2;
  const int so = (t & 3) * 8;

  f32x16 acc[2][2];
  #pragma unroll
  for (int i = 0; i < 2; ++i)
    #pragma unroll
    for (int j = 0; j < 2; ++j)
      #pragma unroll
      for (int r = 0; r < 16; ++r) acc[i][j][r] = 0.f;

  half8 rah[2], rbh[2];
  #pragma unroll
  for (int i = 0; i < 2; ++i) {
    rah[i] = *(const half8*)(Ah + (size_t)(row0 + sr + i * 64) * M_ + so);
    rbh[i] = *(const half8*)(Wt + (size_t)(col0 + sr + i * 64) * M_ + so);
  }

  for (int k0 = 0; k0 < M_; k0 += 32) {
    #pragma unroll
    for (int i = 0; i < 2; ++i) {
      int r = sr + i * 64;
      lds_st8(&Ash[r * 36 + so], rah[i]);
      lds_st8(&Bsh[r * 36 + so], rbh[i]);
    }
    __syncthreads();
    if (k0 + 32 < M_) {
      #pragma unroll
      for (int i = 0; i < 2; ++i) {
        rah[i] = *(const half8*)(Ah + (size_t)(row0 + sr + i * 64) * M_ + k0 + 32 + so);
        rbh[i] = *(const half8*)(Wt + (size_t)(col0 + sr + i * 64) * M_ + k0 + 32 + so);
      }
    }
    #pragma unroll
    for (int c = 0; c < 2; ++c) {
      half8 ah[2], bh[2];
      #pragma unroll
      for (int i = 0; i < 2; ++i) {
        ah[i] = lds_ld8(&Ash[(wr * 64 + i * 32 + lr) * 36 + c * 16 + hh * 8]);
        bh[i] = lds_ld8(&Bsh[(wc * 64 + i * 32 + lr) * 36 + c * 16 + hh * 8]);
      }
      __builtin_amdgcn_s_setprio(1);
      #pragma unroll
      for (int i = 0; i < 2; ++i)
        #pragma unroll
        for (int j = 0; j < 2; ++j)
          acc[i][j] = MFMA32(ah[i], bh[j], acc[i][j]);
      __builtin_amdgcn_s_setprio(0);
    }
    __syncthreads();
  }

  #pragma unroll
  for (int j = 0; j < 2; ++j) {
    const int cc = col0 + wc * 64 + j * 32 + lr;
    const float bs = bias[cc];
    #pragma unroll
    for (int i = 0; i < 2; ++i)
      #pragma unroll
      for (int r = 0; r < 16; ++r) {
        const int rrow = row0 + wr * 64 + i * 32 + (r & 3) + 8 * (r >> 2) + 4 * hh;
        C[(size_t)rrow * M_ + cc] = acc[i][j][r] + bs;
      }
  }
}

extern "C" void kernel_launch(void* const* d_in, const int* in_sizes, int n_in,
                              void* d_out, int out_size, void* d_ws, size_t ws_size,
                              hipStream_t stream) {
  const float* inp    = (const float*)d_in[0];
  const float* mask   = (const float*)d_in[1];
  const float* pre_w  = (const float*)d_in[2];
  const float* pre_b  = (const float*)d_in[3];
  const float* post_w = (const float*)d_in[4];
  const float* post_b = (const float*)d_in[5];
  float* out = (float*)d_out;

  const size_t AE  = (size_t)NR_ * M_;        // 16,777,216
  const size_t HNE = (size_t)H_ * NR_ * D_;   // 16,777,216

  _Float16* a_hi   = (_Float16*)d_ws;         // aliased by attn_h after qkv
  _Float16* a_lo   = a_hi + AE;
  _Float16* w2t_hi = a_lo + AE;               // (1536,512)
  _Float16* w2t_lo = w2t_hi + (size_t)1536 * M_;
  _Float16* pwt    = w2t_lo + (size_t)1536 * M_;   // (512,512)
  _Float16* q_hi   = pwt + (size_t)M_ * M_;
  _Float16* q_lo   = q_hi + HNE;
  _Float16* k_hi   = q_lo + HNE;
  _Float16* k_lo   = k_hi + HNE;
  _Float16* v_h    = k_lo + HNE;
  float*    mask2  = (float*)(v_h + HNE);     // (1024,1024) f32
  _Float16* attn_h = a_hi;                    // reuse (a_hi dead after qkv)

  split_a<<<8192, 256, 0, stream>>>(inp, a_hi, a_lo);
  split_pre_w<<<384, 256, 0, stream>>>(pre_w, w2t_hi, w2t_lo);
  split_post_w<<<128, 256, 0, stream>>>(post_w, pwt);
  scale_mask<<<1024, 256, 0, stream>>>(mask, mask2);

  qkv_mfma<true><<<dim3(8, 256), 256, 0, stream>>>(
      a_hi, a_lo, w2t_hi, w2t_lo, pre_b, 0, q_hi, q_lo, k_hi, k_lo, v_h);
  qkv_mfma<false><<<dim3(4, 256), 256, 0, stream>>>(
      a_hi, a_lo, w2t_hi, w2t_lo, pre_b, 8, q_hi, q_lo, k_hi, k_lo, v_h);

  attn_mfma<<<2048, 256, 0, stream>>>(q_hi, q_lo, k_hi, k_lo, v_h,
                                      mask2, attn_h);

  post_mfma<<<dim3(4, 256), 256, 0, stream>>>(attn_h, pwt, post_b, out);
}

// Round 7
// 466.408 us; speedup vs baseline: 5.1367x; 1.0662x over previous
//
#include <hip/hip_runtime.h>

#define H_ 8
#define B_ 32
#define L_ 1024
#define D_ 64
#define M_ 512
#define NR_ 32768  // B_*L_
#define LOG2E 1.44269504088896340736f

typedef _Float16 half8 __attribute__((ext_vector_type(8)));
typedef _Float16 half4 __attribute__((ext_vector_type(4)));
typedef float f32x16 __attribute__((ext_vector_type(16)));
typedef unsigned int uint2v __attribute__((ext_vector_type(2)));
typedef unsigned int uint4v __attribute__((ext_vector_type(4)));

#define MFMA32(A, B, C) __builtin_amdgcn_mfma_f32_32x32x16_f16(A, B, C, 0, 0, 0)

static __device__ __forceinline__ unsigned pkh(float a, float b) {
  return __builtin_bit_cast(unsigned, __builtin_amdgcn_cvt_pkrtz(a, b));
}
// 8B-aligned LDS moves (row strides 36/68 halves are 8B- but not 16B-aligned)
static __device__ __forceinline__ half8 lds_ld8(const _Float16* p) {
  half4 a = *(const half4*)p;
  half4 b = *(const half4*)(p + 4);
  return __builtin_shufflevector(a, b, 0, 1, 2, 3, 4, 5, 6, 7);
}
static __device__ __forceinline__ void lds_st8(_Float16* p, half8 v) {
  *(half4*)p       = __builtin_shufflevector(v, v, 0, 1, 2, 3);
  *(half4*)(p + 4) = __builtin_shufflevector(v, v, 4, 5, 6, 7);
}
struct half2s { _Float16 h, l; };
static __device__ __forceinline__ half2s split1(float x) {
  half2s r;
  r.h = (_Float16)x;
  r.l = (_Float16)(x - (float)r.h);
  return r;
}

// ---------------------------------------------------------------------------
// split_a: inp (32768x512 f32) -> a_hi, a_lo fp16 (same layout)
// ---------------------------------------------------------------------------
__global__ __launch_bounds__(256) void split_a(
    const float* __restrict__ in, _Float16* __restrict__ hi, _Float16* __restrict__ lo)
{
  const size_t i = (size_t)blockIdx.x * 256 + threadIdx.x;  // per 8 elems
  float4 a = ((const float4*)in)[i * 2];
  float4 b = ((const float4*)in)[i * 2 + 1];
  float v[8] = {a.x, a.y, a.z, a.w, b.x, b.y, b.z, b.w};
  half8 h, l;
  #pragma unroll
  for (int j = 0; j < 8; ++j) {
    half2s s = split1(v[j]);
    h[j] = s.h;
    l[j] = s.l;
  }
  *(half8*)(hi + i * 8) = h;
  *(half8*)(lo + i * 8) = l;
}

// ---------------------------------------------------------------------------
// split_pre_w: pre_w (24,512,64) f32 -> w2t_hi/lo (1536,512) fp16 transposed
// ---------------------------------------------------------------------------
__global__ __launch_bounds__(256) void split_pre_w(
    const float* __restrict__ w, _Float16* __restrict__ hi, _Float16* __restrict__ lo)
{
  const int gid = blockIdx.x * 256 + threadIdx.x;  // 98304 total
  const int cc = gid >> 6;
  const int m0 = (gid & 63) << 3;
  const int g = cc >> 6, d = cc & 63;
  half8 h, l;
  #pragma unroll
  for (int j = 0; j < 8; ++j) {
    half2s s = split1(w[((size_t)g * M_ + m0 + j) * D_ + d]);
    h[j] = s.h;
    l[j] = s.l;
  }
  *(half8*)(hi + (size_t)cc * M_ + m0) = h;
  *(half8*)(lo + (size_t)cc * M_ + m0) = l;
}

// ---------------------------------------------------------------------------
// split_post_w: post_w (512,512) f32 -> pwt (512,512) fp16 transposed
// ---------------------------------------------------------------------------
__global__ __launch_bounds__(256) void split_post_w(
    const float* __restrict__ w, _Float16* __restrict__ hi)
{
  const int gid = blockIdx.x * 256 + threadIdx.x;  // 32768 total
  const int cc = gid >> 6;
  const int m0 = (gid & 63) << 3;
  half8 h;
  #pragma unroll
  for (int j = 0; j < 8; ++j) h[j] = (_Float16)w[(size_t)(m0 + j) * M_ + cc];
  *(half8*)(hi + (size_t)cc * M_ + m0) = h;
}

// ---------------------------------------------------------------------------
// scale_mask: mask2 = mask * log2(e)  (so attn can use exp2 directly)
// ---------------------------------------------------------------------------
__global__ __launch_bounds__(256) void scale_mask(
    const float* __restrict__ in, float* __restrict__ out)
{
  const size_t i = (size_t)blockIdx.x * 256 + threadIdx.x;  // per float4
  float4 v = ((const float4*)in)[i];
  float4 r = {v.x * LOG2E, v.y * LOG2E, v.z * LOG2E, v.w * LOG2E};
  ((float4*)out)[i] = r;
}

// ---------------------------------------------------------------------------
// qkv_mfma: C(32768 x 1536) = A x W^T-stored, fp16 hi/lo split GEMM.
// THREE=true (q,k): 3-term product, outputs hi/lo fp16, Q pre-scaled log2(e).
// THREE=false (v): 1-term, output written TRANSPOSED per (hd,b):
//   vt[((hd*32 + b)*64 + d)*1024 + l]  (half4-vectorized along l)
// ---------------------------------------------------------------------------
template <bool THREE>
__global__ __launch_bounds__(256, 2) void qkv_mfma(
    const _Float16* __restrict__ Ahi, const _Float16* __restrict__ Alo,
    const _Float16* __restrict__ Whi, const _Float16* __restrict__ Wlo,
    const float* __restrict__ bias, int cb0,
    _Float16* __restrict__ qh, _Float16* __restrict__ ql,
    _Float16* __restrict__ kh, _Float16* __restrict__ kl,
    _Float16* __restrict__ vt)
{
  __shared__ _Float16 Ash[128 * 36];
  __shared__ _Float16 Bsh[128 * 36];
  __shared__ _Float16 Asl[THREE ? 128 * 36 : 8];
  __shared__ _Float16 Bsl[THREE ? 128 * 36 : 8];

  const int t = threadIdx.x;
  const int lane = t & 63, w = t >> 6;
  const int wr = w >> 1, wc = w & 1;
  const int lr = lane & 31, hh = lane >> 5;
  const int col0 = (cb0 + blockIdx.x) * 128;
  const int row0 = blockIdx.y * 128;

  const int sr = t >> 2;
  const int so = (t & 3) * 8;

  f32x16 acc[2][2];
  #pragma unroll
  for (int i = 0; i < 2; ++i)
    #pragma unroll
    for (int j = 0; j < 2; ++j)
      #pragma unroll
      for (int r = 0; r < 16; ++r) acc[i][j][r] = 0.f;

  half8 rah[2], ral[2], rbh[2], rbl[2];
  #pragma unroll
  for (int i = 0; i < 2; ++i) {
    size_t ga = (size_t)(row0 + sr + i * 64) * M_ + so;
    size_t gb = (size_t)(col0 + sr + i * 64) * M_ + so;
    rah[i] = *(const half8*)(Ahi + ga);
    rbh[i] = *(const half8*)(Whi + gb);
    if (THREE) { ral[i] = *(const half8*)(Alo + ga); rbl[i] = *(const half8*)(Wlo + gb); }
  }

  for (int k0 = 0; k0 < M_; k0 += 32) {
    #pragma unroll
    for (int i = 0; i < 2; ++i) {
      int r = sr + i * 64;
      lds_st8(&Ash[r * 36 + so], rah[i]);
      lds_st8(&Bsh[r * 36 + so], rbh[i]);
      if (THREE) { lds_st8(&Asl[r * 36 + so], ral[i]); lds_st8(&Bsl[r * 36 + so], rbl[i]); }
    }
    __syncthreads();
    if (k0 + 32 < M_) {
      #pragma unroll
      for (int i = 0; i < 2; ++i) {
        size_t ga = (size_t)(row0 + sr + i * 64) * M_ + k0 + 32 + so;
        size_t gb = (size_t)(col0 + sr + i * 64) * M_ + k0 + 32 + so;
        rah[i] = *(const half8*)(Ahi + ga);
        rbh[i] = *(const half8*)(Whi + gb);
        if (THREE) { ral[i] = *(const half8*)(Alo + ga); rbl[i] = *(const half8*)(Wlo + gb); }
      }
    }
    #pragma unroll
    for (int c = 0; c < 2; ++c) {
      half8 ah[2], bh[2], al[2], bl[2];
      #pragma unroll
      for (int i = 0; i < 2; ++i) {
        const int ar = (wr * 64 + i * 32 + lr) * 36 + c * 16 + hh * 8;
        const int br = (wc * 64 + i * 32 + lr) * 36 + c * 16 + hh * 8;
        ah[i] = lds_ld8(&Ash[ar]);
        bh[i] = lds_ld8(&Bsh[br]);
        if (THREE) { al[i] = lds_ld8(&Asl[ar]); bl[i] = lds_ld8(&Bsl[br]); }
      }
      __builtin_amdgcn_s_setprio(1);
      #pragma unroll
      for (int i = 0; i < 2; ++i)
        #pragma unroll
        for (int j = 0; j < 2; ++j) {
          acc[i][j] = MFMA32(ah[i], bh[j], acc[i][j]);
          if (THREE) {
            acc[i][j] = MFMA32(ah[i], bl[j], acc[i][j]);
            acc[i][j] = MFMA32(al[i], bh[j], acc[i][j]);
          }
        }
      __builtin_amdgcn_s_setprio(0);
    }
    __syncthreads();
  }

  #pragma unroll
  for (int j = 0; j < 2; ++j) {
    const int cc = col0 + wc * 64 + j * 32 + lr;
    const int g = cc >> 6;
    const int t3 = g >> 3, hd = g & 7;
    const int d = cc & 63;
    const float bs = bias[cc];
    #pragma unroll
    for (int i = 0; i < 2; ++i) {
      if (THREE) {
        #pragma unroll
        for (int r = 0; r < 16; ++r) {
          const int rrow = row0 + wr * 64 + i * 32 + (r & 3) + 8 * (r >> 2) + 4 * hh;
          const float x = acc[i][j][r] + bs;
          const size_t base = ((size_t)hd * NR_ + rrow) * D_ + d;
          if (t3 == 0) {
            half2s s = split1(x * LOG2E);   // fold log2(e) into Q
            qh[base] = s.h; ql[base] = s.l;
          } else {
            half2s s = split1(x);
            kh[base] = s.h; kl[base] = s.l;
          }
        }
      } else {
        // v: transposed layout, half4 stores along l (consecutive r&3)
        #pragma unroll
        for (int m = 0; m < 4; ++m) {
          const int rbase = row0 + wr * 64 + i * 32 + 8 * m + 4 * hh;
          const int bb = rbase >> 10;
          const int ll = rbase & 1023;
          half4 v4;
          #pragma unroll
          for (int u = 0; u < 4; ++u) v4[u] = (_Float16)(acc[i][j][4 * m + u] + bs);
          *(half4*)(vt + (((size_t)hd * 32 + bb) * 64 + d) * 1024 + ll) = v4;
        }
      }
    }
  }
}

// ---------------------------------------------------------------------------
// attn_mfma v4: VALU diet. Mask folded into MFMA C-init; V pre-transposed by
// producer (staging = same clean row-major pattern as K, no scatter, no
// 16x ds_write_b16); launch_bounds(256,2) gives 256-reg budget so S/O stay
// in arch VGPRs (no accvgpr shuffling). Double-buffered K/V via registers.
// ---------------------------------------------------------------------------
__global__ __launch_bounds__(256, 2) void attn_mfma(
    const _Float16* __restrict__ qh, const _Float16* __restrict__ ql,
    const _Float16* __restrict__ kh, const _Float16* __restrict__ kl,
    const _Float16* __restrict__ vt,  // (8,32,64,1024) halves: [hd][b][d][l]
    const float* __restrict__ mask2,  // (1024,1024), pre-scaled by log2(e)
    _Float16* __restrict__ outa)      // (32768, 512) fp16
{
  constexpr int ST = 68;              // halves; 8B-aligned rows
  __shared__ _Float16 KhS[2][64 * ST];
  __shared__ _Float16 KlS[2][64 * ST];
  __shared__ _Float16 VtS[2][64 * ST];   // [d][k] row-major

  const int t    = threadIdx.x;
  const int lane = t & 63, w = t >> 6;
  const int lq   = lane & 31, hh = lane >> 5;
  const int id = blockIdx.x;          // 2048 linear
  const int qt = id & 7;
  const int bh = id >> 3;
  const int b  = bh & 31;
  const int hd = bh >> 5;

  const int q_row = qt * 128 + w * 32 + lq;
  const size_t headoff = (size_t)hd * NR_ * D_ + (size_t)b * L_ * D_;

  const size_t qbase = headoff + (size_t)q_row * D_;
  half8 Qhc[4], Qlc[4];
  #pragma unroll
  for (int c = 0; c < 4; ++c) {
    Qhc[c] = *(const half8*)(qh + qbase + c * 16 + hh * 8);
    Qlc[c] = *(const half8*)(ql + qbase + c * 16 + hh * 8);
  }

  const _Float16* Kph = kh + headoff;
  const _Float16* Kpl = kl + headoff;
  const _Float16* Vtp = vt + ((size_t)hd * 32 + b) * (64 * 1024);  // [d][l]
  const float*   mrow = mask2 + (size_t)q_row * L_;

  const int srow = t >> 2;            // 0..63
  const int soff = (t & 3) * 16;      // 0,16,32,48 halves

  float m_i = -3.0e38f, l_i = 0.f;
  f32x16 O0, O1;
  #pragma unroll
  for (int i = 0; i < 16; ++i) { O0[i] = 0.f; O1[i] = 0.f; }

  // staging registers (next K/V tile in flight)
  half8 rkh0, rkh1, rkl0, rkl1, rv0, rv1;
  {
    const size_t goff  = (size_t)srow * D_ + soff;        // K tile kt=0
    const size_t goffv = (size_t)srow * 1024 + soff;      // V^T tile kt=0
    rkh0 = *(const half8*)(Kph + goff);
    rkh1 = *(const half8*)(Kph + goff + 8);
    rkl0 = *(const half8*)(Kpl + goff);
    rkl1 = *(const half8*)(Kpl + goff + 8);
    rv0  = *(const half8*)(Vtp + goffv);
    rv1  = *(const half8*)(Vtp + goffv + 8);
  }
  {
    lds_st8(&KhS[0][srow * ST + soff],     rkh0);
    lds_st8(&KhS[0][srow * ST + soff + 8], rkh1);
    lds_st8(&KlS[0][srow * ST + soff],     rkl0);
    lds_st8(&KlS[0][srow * ST + soff + 8], rkl1);
    lds_st8(&VtS[0][srow * ST + soff],     rv0);
    lds_st8(&VtS[0][srow * ST + soff + 8], rv1);
  }

  for (int kt = 0; kt < 16; ++kt) {
    const int cur = kt & 1;

    // mask loads for this kt (independent of LDS; covered by barrier wait)
    float4 mc[8];
    #pragma unroll
    for (int m = 0; m < 8; ++m)
      mc[m] = *(const float4*)(mrow + kt * 64 + (m >> 2) * 32 + (m & 3) * 8 + hh * 4);

    __syncthreads();   // buf[cur] complete

    // issue next-tile global loads (consumed at end-of-iter LDS write)
    if (kt + 1 < 16) {
      const size_t goff  = (size_t)((kt + 1) * 64 + srow) * D_ + soff;
      const size_t goffv = (size_t)srow * 1024 + (kt + 1) * 64 + soff;
      rkh0 = *(const half8*)(Kph + goff);
      rkh1 = *(const half8*)(Kph + goff + 8);
      rkl0 = *(const half8*)(Kpl + goff);
      rkl1 = *(const half8*)(Kpl + goff + 8);
      rv0  = *(const half8*)(Vtp + goffv);
      rv1  = *(const half8*)(Vtp + goffv + 8);
    }

    const _Float16* Kh = KhS[cur];
    const _Float16* Kl = KlS[cur];
    const _Float16* Vt = VtS[cur];

    // ---- S^T = K . Q + mask (mask pre-loaded into the MFMA C-init) ----
    f32x16 S[2];
    #pragma unroll
    for (int s2 = 0; s2 < 2; ++s2) {
      f32x16 acc;
      #pragma unroll
      for (int m = 0; m < 4; ++m) {
        float4 mv = mc[s2 * 4 + m];
        acc[4 * m + 0] = mv.x;
        acc[4 * m + 1] = mv.y;
        acc[4 * m + 2] = mv.z;
        acc[4 * m + 3] = mv.w;
      }
      #pragma unroll
      for (int c = 0; c < 4; ++c) {
        half8 ah = lds_ld8(&Kh[(s2 * 32 + lq) * ST + c * 16 + hh * 8]);
        half8 al = lds_ld8(&Kl[(s2 * 32 + lq) * ST + c * 16 + hh * 8]);
        __builtin_amdgcn_s_setprio(1);
        acc = MFMA32(ah, Qhc[c], acc);
        acc = MFMA32(ah, Qlc[c], acc);
        acc = MFMA32(al, Qhc[c], acc);
        __builtin_amdgcn_s_setprio(0);
      }
      S[s2] = acc;
    }

    // ---- tile max (max3-friendly tree) ----
    float pm[8];
    #pragma unroll
    for (int g4 = 0; g4 < 8; ++g4) {
      const int s2 = g4 >> 2, m = g4 & 3;
      pm[g4] = fmaxf(fmaxf(S[s2][4 * m + 0], S[s2][4 * m + 1]),
                     fmaxf(S[s2][4 * m + 2], S[s2][4 * m + 3]));
    }
    float tmax = fmaxf(fmaxf(fmaxf(pm[0], pm[1]), fmaxf(pm[2], pm[3])),
                       fmaxf(fmaxf(pm[4], pm[5]), fmaxf(pm[6], pm[7])));
    tmax = fmaxf(tmax, __shfl_xor(tmax, 32, 64));

    // ---- defer-max: only rescale when the tile max grows past m_i + 8 ----
    if (!__all(tmax - m_i <= 8.0f)) {
      float mn = fmaxf(m_i, tmax);
      float sc = exp2f(m_i - mn);
      m_i = mn;
      l_i *= sc;
      O0 = O0 * sc;
      O1 = O1 * sc;
    }

    float rs = 0.f;
    #pragma unroll
    for (int s2 = 0; s2 < 2; ++s2)
      #pragma unroll
      for (int r = 0; r < 16; ++r) {
        float e = exp2f(S[s2][r] - m_i);
        S[s2][r] = e;
        rs += e;
      }
    rs += __shfl_xor(rs, 32, 64);
    l_i += rs;

    // ---- O^T += V^T . P^T ; P^T frags via cvt_pkrtz + permlane32_swap ----
    #pragma unroll
    for (int kc = 0; kc < 4; ++kc) {
      const int s2 = kc >> 1, a2 = kc & 1;
      unsigned x0 = pkh(S[s2][8 * a2 + 0], S[s2][8 * a2 + 1]);
      unsigned x1 = pkh(S[s2][8 * a2 + 2], S[s2][8 * a2 + 3]);
      unsigned y0 = pkh(S[s2][8 * a2 + 4], S[s2][8 * a2 + 5]);
      unsigned y1 = pkh(S[s2][8 * a2 + 6], S[s2][8 * a2 + 7]);
      uint2v r0 = __builtin_amdgcn_permlane32_swap(x0, y0, false, false);
      uint2v r1 = __builtin_amdgcn_permlane32_swap(x1, y1, false, false);
      uint4v wv;
      wv.x = r0.x; wv.y = r1.x; wv.z = r0.y; wv.w = r1.y;
      half8 pfrag = __builtin_bit_cast(half8, wv);
      half8 va = lds_ld8(&Vt[lq * ST + kc * 16 + hh * 8]);
      half8 vb = lds_ld8(&Vt[(32 + lq) * ST + kc * 16 + hh * 8]);
      __builtin_amdgcn_s_setprio(1);
      O0 = MFMA32(va, pfrag, O0);
      O1 = MFMA32(vb, pfrag, O1);
      __builtin_amdgcn_s_setprio(0);
    }

    // ---- write next tile into the other buffer ----
    if (kt + 1 < 16) {
      _Float16* Kh2 = KhS[cur ^ 1];
      _Float16* Kl2 = KlS[cur ^ 1];
      _Float16* Vt2 = VtS[cur ^ 1];
      lds_st8(&Kh2[srow * ST + soff],     rkh0);
      lds_st8(&Kh2[srow * ST + soff + 8], rkh1);
      lds_st8(&Kl2[srow * ST + soff],     rkl0);
      lds_st8(&Kl2[srow * ST + soff + 8], rkl1);
      lds_st8(&Vt2[srow * ST + soff],     rv0);
      lds_st8(&Vt2[srow * ST + soff + 8], rv1);
    }
  }

  float inv = 1.0f / l_i;
  _Float16* orow = outa + ((size_t)b * L_ + q_row) * M_ + hd * 64;
  #pragma unroll
  for (int m = 0; m < 4; ++m) {
    half4 v0 = {(_Float16)(O0[4 * m + 0] * inv), (_Float16)(O0[4 * m + 1] * inv),
                (_Float16)(O0[4 * m + 2] * inv), (_Float16)(O0[4 * m + 3] * inv)};
    *(half4*)(orow + m * 8 + hh * 4) = v0;
    half4 v1 = {(_Float16)(O1[4 * m + 0] * inv), (_Float16)(O1[4 * m + 1] * inv),
                (_Float16)(O1[4 * m + 2] * inv), (_Float16)(O1[4 * m + 3] * inv)};
    *(half4*)(orow + 32 + m * 8 + hh * 4) = v1;
  }
}

// ---------------------------------------------------------------------------
// post_mfma: out(32768x512 f32) = attn_h(f16) x pwt(f16) + bias
// ---------------------------------------------------------------------------
__global__ __launch_bounds__(256, 2) void post_mfma(
    const _Float16* __restrict__ Ah, const _Float16* __restrict__ Wt,
    const float* __restrict__ bias, float* __restrict__ C)
{
  __shared__ _Float16 Ash[128 * 36];
  __shared__ _Float16 Bsh[128 * 36];

  const int t = threadIdx.x;
  const int lane = t & 63, w = t >> 6;
  const int wr = w >> 1, wc = w & 1;
  const int lr = lane & 31, hh = lane >> 5;
  const int col0 = blockIdx.x * 128;
  const int row0 = blockIdx.y * 128;

  const int sr = t >> 2;
  const int so = (t & 3) * 8;

  f32x16 acc[2][2];
  #pragma unroll
  for (int i = 0; i < 2; ++i)
    #pragma unroll
    for (int j = 0; j < 2; ++j)
      #pragma unroll
      for (int r = 0; r < 16; ++r) acc[i][j][r] = 0.f;

  half8 rah[2], rbh[2];
  #pragma unroll
  for (int i = 0; i < 2; ++i) {
    rah[i] = *(const half8*)(Ah + (size_t)(row0 + sr + i * 64) * M_ + so);
    rbh[i] = *(const half8*)(Wt + (size_t)(col0 + sr + i * 64) * M_ + so);
  }

  for (int k0 = 0; k0 < M_; k0 += 32) {
    #pragma unroll
    for (int i = 0; i < 2; ++i) {
      int r = sr + i * 64;
      lds_st8(&Ash[r * 36 + so], rah[i]);
      lds_st8(&Bsh[r * 36 + so], rbh[i]);
    }
    __syncthreads();
    if (k0 + 32 < M_) {
      #pragma unroll
      for (int i = 0; i < 2; ++i) {
        rah[i] = *(const half8*)(Ah + (size_t)(row0 + sr + i * 64) * M_ + k0 + 32 + so);
        rbh[i] = *(const half8*)(Wt + (size_t)(col0 + sr + i * 64) * M_ + k0 + 32 + so);
      }
    }
    #pragma unroll
    for (int c = 0; c < 2; ++c) {
      half8 ah[2], bh[2];
      #pragma unroll
      for (int i = 0; i < 2; ++i) {
        ah[i] = lds_ld8(&Ash[(wr * 64 + i * 32 + lr) * 36 + c * 16 + hh * 8]);
        bh[i] = lds_ld8(&Bsh[(wc * 64 + i * 32 + lr) * 36 + c * 16 + hh * 8]);
      }
      __builtin_amdgcn_s_setprio(1);
      #pragma unroll
      for (int i = 0; i < 2; ++i)
        #pragma unroll
        for (int j = 0; j < 2; ++j)
          acc[i][j] = MFMA32(ah[i], bh[j], acc[i][j]);
      __builtin_amdgcn_s_setprio(0);
    }
    __syncthreads();
  }

  #pragma unroll
  for (int j = 0; j < 2; ++j) {
    const int cc = col0 + wc * 64 + j * 32 + lr;
    const float bs = bias[cc];
    #pragma unroll
    for (int i = 0; i < 2; ++i)
      #pragma unroll
      for (int r = 0; r < 16; ++r) {
        const int rrow = row0 + wr * 64 + i * 32 + (r & 3) + 8 * (r >> 2) + 4 * hh;
        C[(size_t)rrow * M_ + cc] = acc[i][j][r] + bs;
      }
  }
}

extern "C" void kernel_launch(void* const* d_in, const int* in_sizes, int n_in,
                              void* d_out, int out_size, void* d_ws, size_t ws_size,
                              hipStream_t stream) {
  const float* inp    = (const float*)d_in[0];
  const float* mask   = (const float*)d_in[1];
  const float* pre_w  = (const float*)d_in[2];
  const float* pre_b  = (const float*)d_in[3];
  const float* post_w = (const float*)d_in[4];
  const float* post_b = (const float*)d_in[5];
  float* out = (float*)d_out;

  const size_t AE  = (size_t)NR_ * M_;        // 16,777,216
  const size_t HNE = (size_t)H_ * NR_ * D_;   // 16,777,216

  _Float16* a_hi   = (_Float16*)d_ws;         // aliased by attn_h after qkv
  _Float16* a_lo   = a_hi + AE;
  _Float16* w2t_hi = a_lo + AE;               // (1536,512)
  _Float16* w2t_lo = w2t_hi + (size_t)1536 * M_;
  _Float16* pwt    = w2t_lo + (size_t)1536 * M_;   // (512,512)
  _Float16* q_hi   = pwt + (size_t)M_ * M_;
  _Float16* q_lo   = q_hi + HNE;
  _Float16* k_hi   = q_lo + HNE;
  _Float16* k_lo   = k_hi + HNE;
  _Float16* v_t    = k_lo + HNE;              // (8,32,64,1024) transposed v
  float*    mask2  = (float*)(v_t + HNE);     // (1024,1024) f32
  _Float16* attn_h = a_hi;                    // reuse (a_hi dead after qkv)

  split_a<<<8192, 256, 0, stream>>>(inp, a_hi, a_lo);
  split_pre_w<<<384, 256, 0, stream>>>(pre_w, w2t_hi, w2t_lo);
  split_post_w<<<128, 256, 0, stream>>>(post_w, pwt);
  scale_mask<<<1024, 256, 0, stream>>>(mask, mask2);

  qkv_mfma<true><<<dim3(8, 256), 256, 0, stream>>>(
      a_hi, a_lo, w2t_hi, w2t_lo, pre_b, 0, q_hi, q_lo, k_hi, k_lo, v_t);
  qkv_mfma<false><<<dim3(4, 256), 256, 0, stream>>>(
      a_hi, a_lo, w2t_hi, w2t_lo, pre_b, 8, q_hi, q_lo, k_hi, k_lo, v_t);

  attn_mfma<<<2048, 256, 0, stream>>>(q_hi, q_lo, k_hi, k_lo, v_t,
                                      mask2, attn_h);

  post_mfma<<<dim3(4, 256), 256, 0, stream>>>(attn_h, pwt, post_b, out);
}